// Round 14
// baseline (186.593 us; speedup 1.0000x reference)
//
#include <hip/hip_runtime.h>

namespace {
constexpr int kV = 256, kO = 128, kE = 1024, kD = 128;
constexpr int kN = kV * kO;    // 32768 nodes
constexpr int kVE = kV * kE;   // 262144 edges
constexpr float kEps = 1e-5f;
}

typedef __attribute__((ext_vector_type(8))) short bf16x8;
typedef __attribute__((ext_vector_type(8))) unsigned short u16x8;
typedef __attribute__((ext_vector_type(4))) float f32x4;

__device__ __forceinline__ unsigned short f2bf(float x) {
  unsigned u = __float_as_uint(x);
  return (unsigned short)((u + 0x7FFFu + ((u >> 16) & 1u)) >> 16);
}
__device__ __forceinline__ float bf2f(unsigned short h) {
  return __uint_as_float((unsigned)h << 16);
}

// ---- K1: per-graph count matrix A[s][o] -> swizzled u16 + degrees +
// fused unit-0 BN1 stats (p1 slot v).
__global__ __launch_bounds__(256) void k_adj(
    const unsigned int* __restrict__ ew, const float* __restrict__ X,
    int* __restrict__ cnt_s, int* __restrict__ cnt_o,
    unsigned short* __restrict__ Au16, float* __restrict__ p1) {
  __shared__ int cnt[kO * kO];  // 64 KiB (reused as float red later)
  __shared__ int degS[kO], degO[kO];
  __shared__ int anyodd;
  int v = blockIdx.x, t = threadIdx.x;
  if (t == 0) anyodd = 0;
  for (int i = t; i < kO * kO; i += 256) cnt[i] = 0;
  __syncthreads();
  int base = v * 3072, loc = 0;
  for (int i = t; i < 3072; i += 256) {
    int g = base + i;
    if ((g & 1) && ew[g] != 0u) loc = 1;
  }
  if (loc) atomicOr(&anyodd, 1);
  __syncthreads();
  bool is64 = (anyodd == 0);
  for (int e = t; e < kE; e += 256) {
    long long eb = (long long)(v * kE + e) * 3;
    unsigned s, o;
    if (is64) { s = ew[2 * eb]; o = ew[2 * (eb + 2)]; }
    else      { s = ew[eb];     o = ew[eb + 2]; }
    s &= 127u; o &= 127u;
    atomicAdd(&cnt[s * kO + o], 1);
  }
  __syncthreads();
  unsigned int* A32 = (unsigned int*)(Au16 + (size_t)v * 16384);
  for (int i2 = t; i2 < 8192; i2 += 256) {
    int i = 2 * i2;
    int row = i >> 7, k = i & 127, kg = k >> 3;
    int j = row * 128 + ((kg ^ (row & 7)) << 3) + (k & 7);
    unsigned lo = (unsigned)cnt[i], hi = (unsigned)cnt[i + 1];
    A32[j >> 1] = lo | (hi << 16);
  }
  if (t < kO) {
    int s = 0;
    for (int c = 0; c < kO; ++c) s += cnt[t * kO + ((c + t) & 127)];
    degS[t] = s;
    cnt_s[v * kO + t] = s;
  } else {
    int tc = t - kO;
    int s = 0;
    for (int r = 0; r < kO; ++r) s += cnt[((r + tc) & 127) * kO + tc];
    degO[tc] = s;
    cnt_o[v * kO + tc] = s;
  }
  __syncthreads();
  int dq = (t & 31) * 4, rg = t >> 5;
  float acc[4][4];
#pragma unroll
  for (int a = 0; a < 4; ++a)
#pragma unroll
    for (int j = 0; j < 4; ++j) acc[a][j] = 0.f;
  for (int k = 0; k < 16; ++k) {
    int row = rg + k * 8;
    float4 xv = *(const float4*)(X + ((size_t)v * kO + row) * kD + dq);
    float wsv = (float)degS[row], wov = (float)degO[row];
    float xs[4] = {xv.x, xv.y, xv.z, xv.w};
#pragma unroll
    for (int j = 0; j < 4; ++j) {
      acc[0][j] += wsv * xs[j];
      acc[1][j] += wsv * xs[j] * xs[j];
      acc[2][j] += wov * xs[j];
      acc[3][j] += wov * xs[j] * xs[j];
    }
  }
  float* red = (float*)cnt;
  for (int st = 0; st < 4; ++st) {
    __syncthreads();
#pragma unroll
    for (int j = 0; j < 4; ++j) red[rg * 128 + dq + j] = acc[st][j];
    __syncthreads();
    if (t < 128) {
      float s = 0.f;
#pragma unroll
      for (int g = 0; g < 8; ++g) s += red[g * 128 + t];
      p1[((size_t)v * 4 + st) * 128 + t] = s;
    }
  }
}

// ---- K1b: split weight matrices into bf16 hi/lo ----
__global__ __launch_bounds__(256) void k_wsplit(
    const float* __restrict__ s0, const float* __restrict__ s1,
    const float* __restrict__ s2, const float* __restrict__ s3,
    unsigned short* __restrict__ h0, unsigned short* __restrict__ l0,
    unsigned short* __restrict__ h1, unsigned short* __restrict__ l1,
    unsigned short* __restrict__ h2, unsigned short* __restrict__ l2,
    unsigned short* __restrict__ h3, unsigned short* __restrict__ l3) {
  const float* s[4] = {s0, s1, s2, s3};
  unsigned short* hh[4] = {h0, h1, h2, h3};
  unsigned short* ll[4] = {l0, l1, l2, l3};
  const int ns[4] = {kD * 2 * kD, kD * kD, kD * 2 * kD, kD * kD};
  int i0 = blockIdx.x * 256 + threadIdx.x, stride = gridDim.x * 256;
#pragma unroll
  for (int a = 0; a < 4; ++a) {
    for (int i = i0; i < ns[a]; i += stride) {
      float x = s[a][i];
      unsigned short hb = f2bf(x);
      hh[a][i] = hb;
      ll[a][i] = f2bf(x - bf2f(hb));
    }
  }
}

// ---- K2: prep: hs/ho = relu(a*x+b) pre-split bf16 hi/lo -> global ----
__global__ __launch_bounds__(256) void k_prep(
    const float* __restrict__ X, const float* __restrict__ coef,
    unsigned short* __restrict__ hsh, unsigned short* __restrict__ hsl,
    unsigned short* __restrict__ hoh, unsigned short* __restrict__ hol) {
  int g = blockIdx.x * 256 + threadIdx.x;  // 0 .. kN*32-1
  int kq = (g & 31) * 4;
  size_t idx = (size_t)(g >> 5) * kD + kq;
  float4 xv = *(const float4*)(X + idx);
  float4 aS = *(const float4*)(coef + kq), bS = *(const float4*)(coef + 128 + kq);
  float4 aO = *(const float4*)(coef + 256 + kq), bO = *(const float4*)(coef + 384 + kq);
  float hs[4] = {fmaxf(aS.x * xv.x + bS.x, 0.f), fmaxf(aS.y * xv.y + bS.y, 0.f),
                 fmaxf(aS.z * xv.z + bS.z, 0.f), fmaxf(aS.w * xv.w + bS.w, 0.f)};
  float ho[4] = {fmaxf(aO.x * xv.x + bO.x, 0.f), fmaxf(aO.y * xv.y + bO.y, 0.f),
                 fmaxf(aO.z * xv.z + bO.z, 0.f), fmaxf(aO.w * xv.w + bO.w, 0.f)};
  ushort4 sh, sl, oh, ol;
  sh.x = f2bf(hs[0]); sl.x = f2bf(hs[0] - bf2f(sh.x));
  sh.y = f2bf(hs[1]); sl.y = f2bf(hs[1] - bf2f(sh.y));
  sh.z = f2bf(hs[2]); sl.z = f2bf(hs[2] - bf2f(sh.z));
  sh.w = f2bf(hs[3]); sl.w = f2bf(hs[3] - bf2f(sh.w));
  oh.x = f2bf(ho[0]); ol.x = f2bf(ho[0] - bf2f(oh.x));
  oh.y = f2bf(ho[1]); ol.y = f2bf(ho[1] - bf2f(oh.y));
  oh.z = f2bf(ho[2]); ol.z = f2bf(ho[2] - bf2f(oh.z));
  oh.w = f2bf(ho[3]); ol.w = f2bf(ho[3] - bf2f(oh.w));
  *(ushort4*)(hsh + idx) = sh; *(ushort4*)(hsl + idx) = sl;
  *(ushort4*)(hoh + idx) = oh; *(ushort4*)(hol + idx) = ol;
}

// ---- K3: finalize BN1 coeffs — 256 blocks (one per column), nslots partials
__global__ __launch_bounds__(256) void k_fin1(
    const float* __restrict__ p1, const float* __restrict__ g1,
    const float* __restrict__ b1, float* __restrict__ coef, int nslots) {
  __shared__ double sS[256], sQ[256];
  int c = blockIdx.x, t = threadIdx.x;
  int half = c >> 7, d = c & 127;
  double S = 0.0, Q = 0.0;
  for (int b = t; b < nslots; b += 256) {
    S += (double)p1[((size_t)b * 4 + half * 2 + 0) * 128 + d];
    Q += (double)p1[((size_t)b * 4 + half * 2 + 1) * 128 + d];
  }
  sS[t] = S; sQ[t] = Q;
  __syncthreads();
  for (int s = 128; s > 0; s >>= 1) {
    if (t < s) { sS[t] += sS[t + s]; sQ[t] += sQ[t + s]; }
    __syncthreads();
  }
  if (t == 0) {
    double m = sS[0] / (double)kVE;
    double var = sQ[0] / (double)kVE - m * m;
    float a = g1[c] / sqrtf((float)var + kEps);
    float beta = b1[c] - (float)m * a;
    coef[half * 256 + d] = a;
    coef[half * 256 + 128 + d] = beta;
  }
}

// ---- K4: FUSED per-graph kernel, 1024 threads, 64 KiB LDS, 3 barriers.
// Main GEMM phase is barrier-free: A-fragments (hs/ho pre-split) straight
// from global, W from global; A-adjacency prefetched into regs at entry
// with phase-D's exact fragment mapping.
__global__ __launch_bounds__(1024, 1) void k_fused1(
    const unsigned short* __restrict__ hsh, const unsigned short* __restrict__ hsl,
    const unsigned short* __restrict__ hoh, const unsigned short* __restrict__ hol,
    const unsigned short* __restrict__ Whi, const unsigned short* __restrict__ Wlo,
    const unsigned short* __restrict__ Au16,
    const int* __restrict__ cnt_s, const float* __restrict__ lb1,
    float* __restrict__ pooled, float* __restrict__ p2) {
  __shared__ __align__(16) unsigned short TsH[16384], TsL[16384];  // yoT / red
  int t = threadIdx.x, v = blockIdx.x;
  int lane = t & 63, wid = t >> 6;        // 16 waves
  int wr = (wid & 7) * 16, ch = wid >> 3; // 16 rows x 64-col half
  int lrow = lane & 15, lkc = lane >> 4;
  int arow = wr + lrow;
  // ---- entry: prefetch this lane's 4 A-fragments (phase-D mapping) ----
  u16x8 au[4];
#pragma unroll
  for (int ks = 0; ks < 4; ++ks) {
    int kg = ks * 4 + lkc;
    au[ks] = *(const u16x8*)(Au16 + (size_t)v * 16384 + arow * 128 +
                             ((kg ^ (arow & 7)) << 3));
  }
  // ---- Phase B: ys + yo GEMMs, all operands from global (no barrier) ----
  f32x4 accS[4], accO[4];
#pragma unroll
  for (int j = 0; j < 4; ++j) {
    accS[j] = (f32x4){0.f, 0.f, 0.f, 0.f};
    accO[j] = (f32x4){0.f, 0.f, 0.f, 0.f};
  }
  for (int ks = 0; ks < 4; ++ks) {
    int kb = ks * 32 + lkc * 8;
    size_t aoff = (size_t)(v * kO + arow) * kD + kb;
    bf16x8 ash = *(const bf16x8*)(hsh + aoff), asl = *(const bf16x8*)(hsl + aoff);
    bf16x8 aoh = *(const bf16x8*)(hoh + aoff), aol = *(const bf16x8*)(hol + aoff);
#pragma unroll
    for (int jp = 0; jp < 2; ++jp) {
      bf16x8 wsh[2], wsl[2], woh[2], wol[2];
#pragma unroll
      for (int p = 0; p < 2; ++p) {
        int j = ch * 64 + (jp * 2 + p) * 16 + lrow;
        size_t wo = (size_t)j * 256 + kb;
        wsh[p] = *(const bf16x8*)(Whi + wo);
        wsl[p] = *(const bf16x8*)(Wlo + wo);
        woh[p] = *(const bf16x8*)(Whi + wo + 128);
        wol[p] = *(const bf16x8*)(Wlo + wo + 128);
      }
#pragma unroll
      for (int p = 0; p < 2; ++p) {
        int jg = jp * 2 + p;
        accS[jg] = __builtin_amdgcn_mfma_f32_16x16x32_bf16(ash, wsh[p], accS[jg], 0, 0, 0);
        accS[jg] = __builtin_amdgcn_mfma_f32_16x16x32_bf16(ash, wsl[p], accS[jg], 0, 0, 0);
        accS[jg] = __builtin_amdgcn_mfma_f32_16x16x32_bf16(asl, wsh[p], accS[jg], 0, 0, 0);
        accO[jg] = __builtin_amdgcn_mfma_f32_16x16x32_bf16(aoh, woh[p], accO[jg], 0, 0, 0);
        accO[jg] = __builtin_amdgcn_mfma_f32_16x16x32_bf16(aoh, wol[p], accO[jg], 0, 0, 0);
        accO[jg] = __builtin_amdgcn_mfma_f32_16x16x32_bf16(aol, woh[p], accO[jg], 0, 0, 0);
      }
    }
  }
  // ---- Phase C: transpose yo -> TsH/TsL (swizzle <<3) ----
#pragma unroll
  for (int jg = 0; jg < 4; ++jg) {
    int d = ch * 64 + jg * 16 + lrow;
#pragma unroll
    for (int q = 0; q < 4; ++q) {
      int o = wr + lkc * 4 + q;
      int addr = d * 128 + (o ^ ((d & 7) << 3));
      float vv = accO[jg][q];
      unsigned short h = f2bf(vv);
      TsH[addr] = h;
      TsL[addr] = f2bf(vv - bf2f(h));
    }
  }
  __syncthreads();
  // ---- Phase D: pool GEMM: A (regs u16 -> hi/lo) x yoT (LDS) ----
  f32x4 accP[4];
#pragma unroll
  for (int j = 0; j < 4; ++j) accP[j] = (f32x4){0.f, 0.f, 0.f, 0.f};
#pragma unroll
  for (int ks = 0; ks < 4; ++ks) {
    int kb = ks * 32 + lkc * 8;
    bf16x8 pah, pal;
#pragma unroll
    for (int e = 0; e < 8; ++e) {
      float c = (float)au[ks][e];
      unsigned short hb = f2bf(c);
      pah[e] = (short)hb;
      pal[e] = (short)f2bf(c - bf2f(hb));
    }
#pragma unroll
    for (int jg = 0; jg < 4; ++jg) {
      int d = ch * 64 + jg * 16 + lrow;
      int qi = d * 128 + (kb ^ ((d & 7) << 3));
      bf16x8 qh = *(const bf16x8*)(TsH + qi), ql = *(const bf16x8*)(TsL + qi);
      accP[jg] = __builtin_amdgcn_mfma_f32_16x16x32_bf16(pah, qh, accP[jg], 0, 0, 0);
      accP[jg] = __builtin_amdgcn_mfma_f32_16x16x32_bf16(pah, ql, accP[jg], 0, 0, 0);
      accP[jg] = __builtin_amdgcn_mfma_f32_16x16x32_bf16(pal, qh, accP[jg], 0, 0, 0);
    }
  }
  // ---- Phase E: pooled + BN2 partials ----
  float lb[4];
#pragma unroll
  for (int jg = 0; jg < 4; ++jg) lb[jg] = lb1[ch * 64 + jg * 16 + lrow];
  float sm[4], sq[4];
#pragma unroll
  for (int jg = 0; jg < 4; ++jg) { sm[jg] = 0.f; sq[jg] = 0.f; }
#pragma unroll
  for (int q = 0; q < 4; ++q) {
    int row = wr + lkc * 4 + q;
    size_t n = (size_t)v * kO + row;
    int cnt = cnt_s[n];
    float inv = (cnt > 0) ? 1.f / (float)cnt : 0.f;
#pragma unroll
    for (int jg = 0; jg < 4; ++jg) {
      int col = ch * 64 + jg * 16 + lrow;
      float pv = 0.f;
      if (cnt > 0) pv = accS[jg][q] + lb[jg] + accP[jg][q] * inv;
      pooled[n * kD + col] = pv;
      sm[jg] += pv; sq[jg] += pv * pv;
    }
  }
  __syncthreads();  // yoT consumed; reuse TsH region as red f32[64][128]
  float* red = (float*)TsH;  // 8192 floats = 32 KiB (spans TsH..TsL start)
  int slot = (wid & 7) * 4 + lkc;  // 0..31; ch selects col-half
#pragma unroll
  for (int jg = 0; jg < 4; ++jg)
    red[(slot * 2 + ch) * 128 + ch * 64 + jg * 16 + lrow] = sm[jg];
  __syncthreads();
  if (t < 128) {
    float s = 0.f;
#pragma unroll
    for (int g = 0; g < 32; ++g) s += red[(g * 2 + (t >> 6)) * 128 + t];
    p2[((size_t)v * 2 + 0) * 128 + t] = s;
  }
  __syncthreads();
#pragma unroll
  for (int jg = 0; jg < 4; ++jg)
    red[(slot * 2 + ch) * 128 + ch * 64 + jg * 16 + lrow] = sq[jg];
  __syncthreads();
  if (t < 128) {
    float s = 0.f;
#pragma unroll
    for (int g = 0; g < 32; ++g) s += red[(g * 2 + (t >> 6)) * 128 + t];
    p2[((size_t)v * 2 + 1) * 128 + t] = s;
  }
}

// ---- K6: finalize BN2 coeffs — 128 blocks (one per column), 256 partials ----
__global__ __launch_bounds__(256) void k_fin2(
    const float* __restrict__ p2, const float* __restrict__ g2,
    const float* __restrict__ b2, float* __restrict__ coef2) {
  __shared__ double sS[256], sQ[256];
  int d = blockIdx.x, t = threadIdx.x;
  double S = (double)p2[((size_t)t * 2 + 0) * 128 + d];
  double Q = (double)p2[((size_t)t * 2 + 1) * 128 + d];
  sS[t] = S; sQ[t] = Q;
  __syncthreads();
  for (int s = 128; s > 0; s >>= 1) {
    if (t < s) { sS[t] += sS[t + s]; sQ[t] += sQ[t + s]; }
    __syncthreads();
  }
  if (t == 0) {
    double m = sS[0] / (double)kN, var = sQ[0] / (double)kN - m * m;
    float a = g2[d] / sqrtf((float)var + kEps);
    float beta = b2[d] - (float)m * a;
    coef2[d] = a; coef2[128 + d] = beta;
  }
}

// ---- K7: W2 GEMM, 64-row x 128-col tiles, 512 blocks (R13, unchanged) ----
template <int STATS>
__global__ __launch_bounds__(256, 2) void k_gemm(
    const float* __restrict__ X,
    const unsigned short* __restrict__ Whi, const unsigned short* __restrict__ Wlo,
    const float* __restrict__ coefA, const float* __restrict__ coefB,
    float* __restrict__ Y, const float* __restrict__ bias, const float* __restrict__ resid,
    const int* __restrict__ cnt_s, const int* __restrict__ cnt_o,
    float* __restrict__ p1out) {
  __shared__ __align__(16) unsigned short AhL[8192], AlL[8192];
  int t = threadIdx.x, rb = blockIdx.x;
  int dq = (t & 31) * 4, rg = t >> 5;
  float4 av = *(const float4*)(coefA + dq);
  float4 bv = *(const float4*)(coefB + dq);
  for (int k = 0; k < 8; ++k) {
    int r = rg + k * 8;
    float4 xv = *(const float4*)(X + ((size_t)rb * 64 + r) * kD + dq);
    float h[4] = {fmaxf(av.x * xv.x + bv.x, 0.f), fmaxf(av.y * xv.y + bv.y, 0.f),
                  fmaxf(av.z * xv.z + bv.z, 0.f), fmaxf(av.w * xv.w + bv.w, 0.f)};
    ushort4 hi, lo;
    hi.x = f2bf(h[0]); lo.x = f2bf(h[0] - bf2f(hi.x));
    hi.y = f2bf(h[1]); lo.y = f2bf(h[1] - bf2f(hi.y));
    hi.z = f2bf(h[2]); lo.z = f2bf(h[2] - bf2f(hi.z));
    hi.w = f2bf(h[3]); lo.w = f2bf(h[3] - bf2f(hi.w));
    int idx = r * 128 + (dq ^ ((r & 7) << 3));
    *(ushort4*)(AhL + idx) = hi;
    *(ushort4*)(AlL + idx) = lo;
  }
  __syncthreads();
  int lane = t & 63, wid = t >> 6;
  int rh = wid & 1, ch = wid >> 1;
  int wr = rh * 32, lrow = lane & 15, lkc = lane >> 4;
  f32x4 acc[2][4];
#pragma unroll
  for (int i = 0; i < 2; ++i)
#pragma unroll
    for (int j = 0; j < 4; ++j) acc[i][j] = (f32x4){0.f, 0.f, 0.f, 0.f};
  for (int ks = 0; ks < 4; ++ks) {
    int kb = ks * 32 + lkc * 8;
    bf16x8 ah[2], al[2];
#pragma unroll
    for (int ri = 0; ri < 2; ++ri) {
      int ar = wr + ri * 16 + lrow;
      int ai = ar * 128 + (kb ^ ((ar & 7) << 3));
      ah[ri] = *(const bf16x8*)(AhL + ai);
      al[ri] = *(const bf16x8*)(AlL + ai);
    }
    bf16x8 bh[4], bl[4];
#pragma unroll
    for (int jg = 0; jg < 4; ++jg) {
      size_t wo = (size_t)(ch * 64 + jg * 16 + lrow) * 128 + kb;
      bh[jg] = *(const bf16x8*)(Whi + wo);
      bl[jg] = *(const bf16x8*)(Wlo + wo);
    }
#pragma unroll
    for (int jg = 0; jg < 4; ++jg)
#pragma unroll
      for (int ri = 0; ri < 2; ++ri) {
        acc[ri][jg] = __builtin_amdgcn_mfma_f32_16x16x32_bf16(ah[ri], bh[jg], acc[ri][jg], 0, 0, 0);
        acc[ri][jg] = __builtin_amdgcn_mfma_f32_16x16x32_bf16(ah[ri], bl[jg], acc[ri][jg], 0, 0, 0);
        acc[ri][jg] = __builtin_amdgcn_mfma_f32_16x16x32_bf16(al[ri], bh[jg], acc[ri][jg], 0, 0, 0);
      }
  }
  float s0[4], s1[4], s2[4], s3[4];
  if (STATS) {
#pragma unroll
    for (int jg = 0; jg < 4; ++jg) { s0[jg] = 0.f; s1[jg] = 0.f; s2[jg] = 0.f; s3[jg] = 0.f; }
  }
#pragma unroll
  for (int ri = 0; ri < 2; ++ri) {
    float wsr[4], wor[4];
    if (STATS) {
#pragma unroll
      for (int q = 0; q < 4; ++q) {
        int n = rb * 64 + wr + ri * 16 + lkc * 4 + q;
        wsr[q] = (float)cnt_s[n]; wor[q] = (float)cnt_o[n];
      }
    }
#pragma unroll
    for (int jg = 0; jg < 4; ++jg) {
      int col = ch * 64 + jg * 16 + lrow;
      float bcol = bias ? bias[col] : 0.f;
#pragma unroll
      for (int q = 0; q < 4; ++q) {
        int row = wr + ri * 16 + lkc * 4 + q;
        size_t n = (size_t)rb * 64 + row;
        float vv = acc[ri][jg][q] + bcol;
        if (resid) vv += resid[n * kD + col];
        Y[n * kD + col] = vv;
        if (STATS) {
          s0[jg] += wsr[q] * vv; s1[jg] += wsr[q] * vv * vv;
          s2[jg] += wor[q] * vv; s3[jg] += wor[q] * vv * vv;
        }
      }
    }
  }
  if (STATS) {
    __syncthreads();
    float* red = (float*)AhL;  // [4 stats][8][128] = 16 KiB
    int slot = rh * 4 + lkc;
#pragma unroll
    for (int jg = 0; jg < 4; ++jg) {
      int col = ch * 64 + jg * 16 + lrow;
      red[0 * 1024 + slot * 128 + col] = s0[jg];
      red[1 * 1024 + slot * 128 + col] = s1[jg];
      red[2 * 1024 + slot * 128 + col] = s2[jg];
      red[3 * 1024 + slot * 128 + col] = s3[jg];
    }
    __syncthreads();
    if (t < 128) {
#pragma unroll
      for (int st = 0; st < 4; ++st) {
        float s = 0.f;
#pragma unroll
        for (int g = 0; g < 8; ++g) s += red[st * 1024 + g * 128 + t];
        p1out[((size_t)rb * 4 + st) * 128 + t] = s;
      }
    }
  }
}

extern "C" void kernel_launch(void* const* d_in, const int* in_sizes, int n_in,
                              void* d_out, int out_size, void* d_ws, size_t ws_size,
                              hipStream_t stream) {
  (void)in_sizes; (void)n_in; (void)out_size; (void)ws_size;
  const float* obj = (const float*)d_in[0];
  const unsigned int* ew = (const unsigned int*)d_in[1];
  const float* prm[2][8];
  for (int u = 0; u < 2; ++u)
    for (int p = 0; p < 8; ++p) prm[u][p] = (const float*)d_in[2 + u * 8 + p];
  // prm[u]: 0=g1 1=b1 2=W1 3=lb1 4=g2 5=b2 6=W2 7=lb2

  char* ws = (char*)d_ws;
  size_t off = 0;
  auto carve = [&](size_t bytes) -> char* {
    char* p = ws + off;
    off = (off + bytes + 255) & ~(size_t)255;
    return p;
  };
  int* cnt_s = (int*)carve((size_t)kN * 4);
  int* cnt_o = (int*)carve((size_t)kN * 4);
  unsigned short* Au16 = (unsigned short*)carve((size_t)kV * 16384 * 2);
  float* p1 = (float*)carve((size_t)512 * 4 * 128 * 4);
  float* p2 = (float*)carve((size_t)kV * 2 * 128 * 4);
  float* coef1 = (float*)carve(512 * 4);
  float* coef2 = (float*)carve(256 * 4);
  unsigned short *w1hi[2], *w1lo[2], *w2hi[2], *w2lo[2];
  for (int u = 0; u < 2; ++u) {
    w1hi[u] = (unsigned short*)carve((size_t)kD * 2 * kD * 2);
    w1lo[u] = (unsigned short*)carve((size_t)kD * 2 * kD * 2);
    w2hi[u] = (unsigned short*)carve((size_t)kD * kD * 2);
    w2lo[u] = (unsigned short*)carve((size_t)kD * kD * 2);
  }
  unsigned short* hsh = (unsigned short*)carve((size_t)kN * kD * 2);
  unsigned short* hsl = (unsigned short*)carve((size_t)kN * kD * 2);
  unsigned short* hoh = (unsigned short*)carve((size_t)kN * kD * 2);
  unsigned short* hol = (unsigned short*)carve((size_t)kN * kD * 2);
  float* pooled = (float*)carve((size_t)kN * kD * 4);
  float* x2 = (float*)carve((size_t)kN * kD * 4);

  k_adj<<<kV, 256, 0, stream>>>(ew, obj, cnt_s, cnt_o, Au16, p1);
  k_wsplit<<<128, 256, 0, stream>>>(prm[0][2], prm[0][6], prm[1][2], prm[1][6],
                                    w1hi[0], w1lo[0], w2hi[0], w2lo[0],
                                    w1hi[1], w1lo[1], w2hi[1], w2lo[1]);

  float* outp = (float*)d_out;
  // ---- unit 0 ----
  k_fin1<<<256, 256, 0, stream>>>(p1, prm[0][0], prm[0][1], coef1, 256);
  k_prep<<<kN / 8, 256, 0, stream>>>(obj, coef1, hsh, hsl, hoh, hol);
  k_fused1<<<kV, 1024, 0, stream>>>(hsh, hsl, hoh, hol, w1hi[0], w1lo[0], Au16,
                                    cnt_s, prm[0][3], pooled, p2);
  k_fin2<<<128, 256, 0, stream>>>(p2, prm[0][4], prm[0][5], coef2);
  k_gemm<1><<<512, 256, 0, stream>>>(pooled, w2hi[0], w2lo[0], coef2, coef2 + 128,
                                     x2, prm[0][7], nullptr, cnt_s, cnt_o, p1);
  // ---- unit 1 ----
  k_fin1<<<256, 256, 0, stream>>>(p1, prm[1][0], prm[1][1], coef1, 512);
  k_prep<<<kN / 8, 256, 0, stream>>>(x2, coef1, hsh, hsl, hoh, hol);
  k_fused1<<<kV, 1024, 0, stream>>>(hsh, hsl, hoh, hol, w1hi[1], w1lo[1], Au16,
                                    cnt_s, prm[1][3], pooled, p2);
  k_fin2<<<128, 256, 0, stream>>>(p2, prm[1][4], prm[1][5], coef2);
  k_gemm<0><<<512, 256, 0, stream>>>(pooled, w2hi[1], w2lo[1], coef2, coef2 + 128,
                                     outp, prm[1][7], obj, nullptr, nullptr, nullptr);
}

// Round 15
// 179.312 us; speedup vs baseline: 1.0406x; 1.0406x over previous
//
#include <hip/hip_runtime.h>

namespace {
constexpr int kV = 256, kO = 128, kE = 1024, kD = 128;
constexpr int kN = kV * kO;    // 32768 nodes
constexpr int kVE = kV * kE;   // 262144 edges
constexpr float kEps = 1e-5f;
}

typedef __attribute__((ext_vector_type(8))) short bf16x8;
typedef __attribute__((ext_vector_type(8))) unsigned short u16x8;
typedef __attribute__((ext_vector_type(4))) float f32x4;

__device__ __forceinline__ unsigned short f2bf(float x) {
  unsigned u = __float_as_uint(x);
  return (unsigned short)((u + 0x7FFFu + ((u >> 16) & 1u)) >> 16);
}
__device__ __forceinline__ float bf2f(unsigned short h) {
  return __uint_as_float((unsigned)h << 16);
}

// ---- K1: per-graph count matrix A[s][o] -> swizzled u16 + degrees +
// fused unit-0 BN1 stats (p1 slot v).
__global__ __launch_bounds__(256) void k_adj(
    const unsigned int* __restrict__ ew, const float* __restrict__ X,
    int* __restrict__ cnt_s, int* __restrict__ cnt_o,
    unsigned short* __restrict__ Au16, float* __restrict__ p1) {
  __shared__ int cnt[kO * kO];  // 64 KiB (reused as float red later)
  __shared__ int degS[kO], degO[kO];
  __shared__ int anyodd;
  int v = blockIdx.x, t = threadIdx.x;
  if (t == 0) anyodd = 0;
  for (int i = t; i < kO * kO; i += 256) cnt[i] = 0;
  __syncthreads();
  int base = v * 3072, loc = 0;
  for (int i = t; i < 3072; i += 256) {
    int g = base + i;
    if ((g & 1) && ew[g] != 0u) loc = 1;
  }
  if (loc) atomicOr(&anyodd, 1);
  __syncthreads();
  bool is64 = (anyodd == 0);
  for (int e = t; e < kE; e += 256) {
    long long eb = (long long)(v * kE + e) * 3;
    unsigned s, o;
    if (is64) { s = ew[2 * eb]; o = ew[2 * (eb + 2)]; }
    else      { s = ew[eb];     o = ew[eb + 2]; }
    s &= 127u; o &= 127u;
    atomicAdd(&cnt[s * kO + o], 1);
  }
  __syncthreads();
  unsigned int* A32 = (unsigned int*)(Au16 + (size_t)v * 16384);
  for (int i2 = t; i2 < 8192; i2 += 256) {
    int i = 2 * i2;
    int row = i >> 7, k = i & 127, kg = k >> 3;
    int j = row * 128 + ((kg ^ (row & 7)) << 3) + (k & 7);
    unsigned lo = (unsigned)cnt[i], hi = (unsigned)cnt[i + 1];
    A32[j >> 1] = lo | (hi << 16);
  }
  if (t < kO) {
    int s = 0;
    for (int c = 0; c < kO; ++c) s += cnt[t * kO + ((c + t) & 127)];
    degS[t] = s;
    cnt_s[v * kO + t] = s;
  } else {
    int tc = t - kO;
    int s = 0;
    for (int r = 0; r < kO; ++r) s += cnt[((r + tc) & 127) * kO + tc];
    degO[tc] = s;
    cnt_o[v * kO + tc] = s;
  }
  __syncthreads();
  int dq = (t & 31) * 4, rg = t >> 5;
  float acc[4][4];
#pragma unroll
  for (int a = 0; a < 4; ++a)
#pragma unroll
    for (int j = 0; j < 4; ++j) acc[a][j] = 0.f;
  for (int k = 0; k < 16; ++k) {
    int row = rg + k * 8;
    float4 xv = *(const float4*)(X + ((size_t)v * kO + row) * kD + dq);
    float wsv = (float)degS[row], wov = (float)degO[row];
    float xs[4] = {xv.x, xv.y, xv.z, xv.w};
#pragma unroll
    for (int j = 0; j < 4; ++j) {
      acc[0][j] += wsv * xs[j];
      acc[1][j] += wsv * xs[j] * xs[j];
      acc[2][j] += wov * xs[j];
      acc[3][j] += wov * xs[j] * xs[j];
    }
  }
  float* red = (float*)cnt;
  for (int st = 0; st < 4; ++st) {
    __syncthreads();
#pragma unroll
    for (int j = 0; j < 4; ++j) red[rg * 128 + dq + j] = acc[st][j];
    __syncthreads();
    if (t < 128) {
      float s = 0.f;
#pragma unroll
      for (int g = 0; g < 8; ++g) s += red[g * 128 + t];
      p1[((size_t)v * 4 + st) * 128 + t] = s;
    }
  }
}

// ---- K1b: split weight matrices into bf16 hi/lo ----
__global__ __launch_bounds__(256) void k_wsplit(
    const float* __restrict__ s0, const float* __restrict__ s1,
    const float* __restrict__ s2, const float* __restrict__ s3,
    unsigned short* __restrict__ h0, unsigned short* __restrict__ l0,
    unsigned short* __restrict__ h1, unsigned short* __restrict__ l1,
    unsigned short* __restrict__ h2, unsigned short* __restrict__ l2,
    unsigned short* __restrict__ h3, unsigned short* __restrict__ l3) {
  const float* s[4] = {s0, s1, s2, s3};
  unsigned short* hh[4] = {h0, h1, h2, h3};
  unsigned short* ll[4] = {l0, l1, l2, l3};
  const int ns[4] = {kD * 2 * kD, kD * kD, kD * 2 * kD, kD * kD};
  int i0 = blockIdx.x * 256 + threadIdx.x, stride = gridDim.x * 256;
#pragma unroll
  for (int a = 0; a < 4; ++a) {
    for (int i = i0; i < ns[a]; i += stride) {
      float x = s[a][i];
      unsigned short hb = f2bf(x);
      hh[a][i] = hb;
      ll[a][i] = f2bf(x - bf2f(hb));
    }
  }
}

// ---- K2: prep: hs/ho = relu(a*x+b) pre-split bf16 hi/lo -> global, written
// in the per-graph SWIZZLED LDS-image layout (32 KB contiguous per graph):
// dest = v*16384 + r*128 + (kq ^ ((r&7)<<3)), kq multiple of 4.
__global__ __launch_bounds__(256) void k_prep(
    const float* __restrict__ X, const float* __restrict__ coef,
    unsigned short* __restrict__ hsh, unsigned short* __restrict__ hsl,
    unsigned short* __restrict__ hoh, unsigned short* __restrict__ hol) {
  int g = blockIdx.x * 256 + threadIdx.x;  // 0 .. kN*32-1
  int kq = (g & 31) * 4;
  int n = g >> 5;
  int v = n >> 7, r = n & 127;
  float4 xv = *(const float4*)(X + (size_t)n * kD + kq);
  float4 aS = *(const float4*)(coef + kq), bS = *(const float4*)(coef + 128 + kq);
  float4 aO = *(const float4*)(coef + 256 + kq), bO = *(const float4*)(coef + 384 + kq);
  float hs[4] = {fmaxf(aS.x * xv.x + bS.x, 0.f), fmaxf(aS.y * xv.y + bS.y, 0.f),
                 fmaxf(aS.z * xv.z + bS.z, 0.f), fmaxf(aS.w * xv.w + bS.w, 0.f)};
  float ho[4] = {fmaxf(aO.x * xv.x + bO.x, 0.f), fmaxf(aO.y * xv.y + bO.y, 0.f),
                 fmaxf(aO.z * xv.z + bO.z, 0.f), fmaxf(aO.w * xv.w + bO.w, 0.f)};
  ushort4 sh, sl, oh, ol;
  sh.x = f2bf(hs[0]); sl.x = f2bf(hs[0] - bf2f(sh.x));
  sh.y = f2bf(hs[1]); sl.y = f2bf(hs[1] - bf2f(sh.y));
  sh.z = f2bf(hs[2]); sl.z = f2bf(hs[2] - bf2f(sh.z));
  sh.w = f2bf(hs[3]); sl.w = f2bf(hs[3] - bf2f(sh.w));
  oh.x = f2bf(ho[0]); ol.x = f2bf(ho[0] - bf2f(oh.x));
  oh.y = f2bf(ho[1]); ol.y = f2bf(ho[1] - bf2f(oh.y));
  oh.z = f2bf(ho[2]); ol.z = f2bf(ho[2] - bf2f(oh.z));
  oh.w = f2bf(ho[3]); ol.w = f2bf(ho[3] - bf2f(oh.w));
  size_t dst = (size_t)v * 16384 + r * 128 + (kq ^ ((r & 7) << 3));
  *(ushort4*)(hsh + dst) = sh; *(ushort4*)(hsl + dst) = sl;
  *(ushort4*)(hoh + dst) = oh; *(ushort4*)(hol + dst) = ol;
}

// ---- K3: finalize BN1 coeffs — 256 blocks (one per column), nslots partials
__global__ __launch_bounds__(256) void k_fin1(
    const float* __restrict__ p1, const float* __restrict__ g1,
    const float* __restrict__ b1, float* __restrict__ coef, int nslots) {
  __shared__ double sS[256], sQ[256];
  int c = blockIdx.x, t = threadIdx.x;
  int half = c >> 7, d = c & 127;
  double S = 0.0, Q = 0.0;
  for (int b = t; b < nslots; b += 256) {
    S += (double)p1[((size_t)b * 4 + half * 2 + 0) * 128 + d];
    Q += (double)p1[((size_t)b * 4 + half * 2 + 1) * 128 + d];
  }
  sS[t] = S; sQ[t] = Q;
  __syncthreads();
  for (int s = 128; s > 0; s >>= 1) {
    if (t < s) { sS[t] += sS[t + s]; sQ[t] += sQ[t + s]; }
    __syncthreads();
  }
  if (t == 0) {
    double m = sS[0] / (double)kVE;
    double var = sQ[0] / (double)kVE - m * m;
    float a = g1[c] / sqrtf((float)var + kEps);
    float beta = b1[c] - (float)m * a;
    coef[half * 256 + d] = a;
    coef[half * 256 + 128 + d] = beta;
  }
}

// ---- K4: FUSED per-graph kernel, 1024 threads, 128 KiB LDS.
// Entry: ASYNC-stage hs/ho (hi/lo) tiles via global_load_lds (8 issues/thr,
// 128 KB in flight) + A-fragment reg prefetch. One drain barrier, then all
// GEMM phases read LDS; W streams from L2.
__global__ __launch_bounds__(1024, 1) void k_fused1(
    const unsigned short* __restrict__ hsh, const unsigned short* __restrict__ hsl,
    const unsigned short* __restrict__ hoh, const unsigned short* __restrict__ hol,
    const unsigned short* __restrict__ Whi, const unsigned short* __restrict__ Wlo,
    const unsigned short* __restrict__ Au16,
    const int* __restrict__ cnt_s, const float* __restrict__ lb1,
    float* __restrict__ pooled, float* __restrict__ p2) {
  __shared__ __align__(16) unsigned short HsH[16384], HsL[16384];
  __shared__ __align__(16) unsigned short HoH[16384], HoL[16384];
  int t = threadIdx.x, v = blockIdx.x;
  int lane = t & 63, wid = t >> 6;        // 16 waves
  int wr = (wid & 7) * 16, ch = wid >> 3; // 16 rows x 64-col half
  int lrow = lane & 15, lkc = lane >> 4;
  int arow = wr + lrow;
  // ---- entry: async stage 4x32KB tiles (LDS-image layout) ----
  {
    const char* gs[4] = {(const char*)(hsh + (size_t)v * 16384),
                         (const char*)(hsl + (size_t)v * 16384),
                         (const char*)(hoh + (size_t)v * 16384),
                         (const char*)(hol + (size_t)v * 16384)};
    char* ls[4] = {(char*)HsH, (char*)HsL, (char*)HoH, (char*)HoL};
    int wb = wid * 2048;  // bytes per wave segment
#pragma unroll
    for (int a = 0; a < 4; ++a)
#pragma unroll
      for (int i = 0; i < 2; ++i)
        __builtin_amdgcn_global_load_lds(
            (const unsigned int*)(gs[a] + wb + i * 1024 + lane * 16),
            (unsigned int*)(ls[a] + wb + i * 1024), 16, 0, 0);
  }
  // A-fragment reg prefetch (phase-D mapping)
  u16x8 au[4];
#pragma unroll
  for (int ks = 0; ks < 4; ++ks) {
    int kg = ks * 4 + lkc;
    au[ks] = *(const u16x8*)(Au16 + (size_t)v * 16384 + arow * 128 +
                             ((kg ^ (arow & 7)) << 3));
  }
  __syncthreads();  // drain staging
  // ---- Phase B: ys + yo GEMMs from LDS; W from global L2 ----
  f32x4 accS[4], accO[4];
#pragma unroll
  for (int j = 0; j < 4; ++j) {
    accS[j] = (f32x4){0.f, 0.f, 0.f, 0.f};
    accO[j] = (f32x4){0.f, 0.f, 0.f, 0.f};
  }
  for (int ks = 0; ks < 4; ++ks) {
    int kb = ks * 32 + lkc * 8;
    int ai = arow * 128 + (kb ^ ((arow & 7) << 3));
    bf16x8 ash = *(const bf16x8*)(HsH + ai), asl = *(const bf16x8*)(HsL + ai);
    bf16x8 aoh = *(const bf16x8*)(HoH + ai), aol = *(const bf16x8*)(HoL + ai);
#pragma unroll
    for (int jp = 0; jp < 2; ++jp) {
      bf16x8 wsh[2], wsl[2], woh[2], wol[2];
#pragma unroll
      for (int p = 0; p < 2; ++p) {
        int j = ch * 64 + (jp * 2 + p) * 16 + lrow;
        size_t wo = (size_t)j * 256 + kb;
        wsh[p] = *(const bf16x8*)(Whi + wo);
        wsl[p] = *(const bf16x8*)(Wlo + wo);
        woh[p] = *(const bf16x8*)(Whi + wo + 128);
        wol[p] = *(const bf16x8*)(Wlo + wo + 128);
      }
#pragma unroll
      for (int p = 0; p < 2; ++p) {
        int jg = jp * 2 + p;
        accS[jg] = __builtin_amdgcn_mfma_f32_16x16x32_bf16(ash, wsh[p], accS[jg], 0, 0, 0);
        accS[jg] = __builtin_amdgcn_mfma_f32_16x16x32_bf16(ash, wsl[p], accS[jg], 0, 0, 0);
        accS[jg] = __builtin_amdgcn_mfma_f32_16x16x32_bf16(asl, wsh[p], accS[jg], 0, 0, 0);
        accO[jg] = __builtin_amdgcn_mfma_f32_16x16x32_bf16(aoh, woh[p], accO[jg], 0, 0, 0);
        accO[jg] = __builtin_amdgcn_mfma_f32_16x16x32_bf16(aoh, wol[p], accO[jg], 0, 0, 0);
        accO[jg] = __builtin_amdgcn_mfma_f32_16x16x32_bf16(aol, woh[p], accO[jg], 0, 0, 0);
      }
    }
  }
  __syncthreads();
  // ---- Phase C: transpose yo -> HsH/HsL (hs consumed; swizzle <<3) ----
#pragma unroll
  for (int jg = 0; jg < 4; ++jg) {
    int d = ch * 64 + jg * 16 + lrow;
#pragma unroll
    for (int q = 0; q < 4; ++q) {
      int o = wr + lkc * 4 + q;
      int addr = d * 128 + (o ^ ((d & 7) << 3));
      float vv = accO[jg][q];
      unsigned short h = f2bf(vv);
      HsH[addr] = h;
      HsL[addr] = f2bf(vv - bf2f(h));
    }
  }
  __syncthreads();
  // ---- Phase D: pool GEMM: A (regs u16 -> hi/lo) x yoT (LDS) ----
  f32x4 accP[4];
#pragma unroll
  for (int j = 0; j < 4; ++j) accP[j] = (f32x4){0.f, 0.f, 0.f, 0.f};
#pragma unroll
  for (int ks = 0; ks < 4; ++ks) {
    int kb = ks * 32 + lkc * 8;
    bf16x8 pah, pal;
#pragma unroll
    for (int e = 0; e < 8; ++e) {
      float c = (float)au[ks][e];
      unsigned short hb = f2bf(c);
      pah[e] = (short)hb;
      pal[e] = (short)f2bf(c - bf2f(hb));
    }
#pragma unroll
    for (int jg = 0; jg < 4; ++jg) {
      int d = ch * 64 + jg * 16 + lrow;
      int qi = d * 128 + (kb ^ ((d & 7) << 3));
      bf16x8 qh = *(const bf16x8*)(HsH + qi), ql = *(const bf16x8*)(HsL + qi);
      accP[jg] = __builtin_amdgcn_mfma_f32_16x16x32_bf16(pah, qh, accP[jg], 0, 0, 0);
      accP[jg] = __builtin_amdgcn_mfma_f32_16x16x32_bf16(pah, ql, accP[jg], 0, 0, 0);
      accP[jg] = __builtin_amdgcn_mfma_f32_16x16x32_bf16(pal, qh, accP[jg], 0, 0, 0);
    }
  }
  // ---- Phase E: pooled + BN2 partials ----
  float lb[4];
#pragma unroll
  for (int jg = 0; jg < 4; ++jg) lb[jg] = lb1[ch * 64 + jg * 16 + lrow];
  float sm[4], sq[4];
#pragma unroll
  for (int jg = 0; jg < 4; ++jg) { sm[jg] = 0.f; sq[jg] = 0.f; }
#pragma unroll
  for (int q = 0; q < 4; ++q) {
    int row = wr + lkc * 4 + q;
    size_t n = (size_t)v * kO + row;
    int cnt = cnt_s[n];
    float inv = (cnt > 0) ? 1.f / (float)cnt : 0.f;
#pragma unroll
    for (int jg = 0; jg < 4; ++jg) {
      int col = ch * 64 + jg * 16 + lrow;
      float pv = 0.f;
      if (cnt > 0) pv = accS[jg][q] + lb[jg] + accP[jg][q] * inv;
      pooled[n * kD + col] = pv;
      sm[jg] += pv; sq[jg] += pv * pv;
    }
  }
  __syncthreads();  // HoH/HoL free; use as red f32[64][128]
  float* red = (float*)HoH;
  int slot = (wid & 7) * 4 + lkc;  // 0..31; ch selects col-half
#pragma unroll
  for (int jg = 0; jg < 4; ++jg)
    red[(slot * 2 + ch) * 128 + ch * 64 + jg * 16 + lrow] = sm[jg];
  __syncthreads();
  if (t < 128) {
    float s = 0.f;
#pragma unroll
    for (int g = 0; g < 32; ++g) s += red[(g * 2 + (t >> 6)) * 128 + t];
    p2[((size_t)v * 2 + 0) * 128 + t] = s;
  }
  __syncthreads();
#pragma unroll
  for (int jg = 0; jg < 4; ++jg)
    red[(slot * 2 + ch) * 128 + ch * 64 + jg * 16 + lrow] = sq[jg];
  __syncthreads();
  if (t < 128) {
    float s = 0.f;
#pragma unroll
    for (int g = 0; g < 32; ++g) s += red[(g * 2 + (t >> 6)) * 128 + t];
    p2[((size_t)v * 2 + 1) * 128 + t] = s;
  }
}

// ---- K6: finalize BN2 coeffs — 128 blocks (one per column), 256 partials ----
__global__ __launch_bounds__(256) void k_fin2(
    const float* __restrict__ p2, const float* __restrict__ g2,
    const float* __restrict__ b2, float* __restrict__ coef2) {
  __shared__ double sS[256], sQ[256];
  int d = blockIdx.x, t = threadIdx.x;
  double S = (double)p2[((size_t)t * 2 + 0) * 128 + d];
  double Q = (double)p2[((size_t)t * 2 + 1) * 128 + d];
  sS[t] = S; sQ[t] = Q;
  __syncthreads();
  for (int s = 128; s > 0; s >>= 1) {
    if (t < s) { sS[t] += sS[t + s]; sQ[t] += sQ[t + s]; }
    __syncthreads();
  }
  if (t == 0) {
    double m = sS[0] / (double)kN, var = sQ[0] / (double)kN - m * m;
    float a = g2[d] / sqrtf((float)var + kEps);
    float beta = b2[d] - (float)m * a;
    coef2[d] = a; coef2[128 + d] = beta;
  }
}

// ---- K7: W2 GEMM, 64-row x 128-col tiles, 512 blocks (R13, unchanged) ----
template <int STATS>
__global__ __launch_bounds__(256, 2) void k_gemm(
    const float* __restrict__ X,
    const unsigned short* __restrict__ Whi, const unsigned short* __restrict__ Wlo,
    const float* __restrict__ coefA, const float* __restrict__ coefB,
    float* __restrict__ Y, const float* __restrict__ bias, const float* __restrict__ resid,
    const int* __restrict__ cnt_s, const int* __restrict__ cnt_o,
    float* __restrict__ p1out) {
  __shared__ __align__(16) unsigned short AhL[8192], AlL[8192];
  int t = threadIdx.x, rb = blockIdx.x;
  int dq = (t & 31) * 4, rg = t >> 5;
  float4 av = *(const float4*)(coefA + dq);
  float4 bv = *(const float4*)(coefB + dq);
  for (int k = 0; k < 8; ++k) {
    int r = rg + k * 8;
    float4 xv = *(const float4*)(X + ((size_t)rb * 64 + r) * kD + dq);
    float h[4] = {fmaxf(av.x * xv.x + bv.x, 0.f), fmaxf(av.y * xv.y + bv.y, 0.f),
                  fmaxf(av.z * xv.z + bv.z, 0.f), fmaxf(av.w * xv.w + bv.w, 0.f)};
    ushort4 hi, lo;
    hi.x = f2bf(h[0]); lo.x = f2bf(h[0] - bf2f(hi.x));
    hi.y = f2bf(h[1]); lo.y = f2bf(h[1] - bf2f(hi.y));
    hi.z = f2bf(h[2]); lo.z = f2bf(h[2] - bf2f(hi.z));
    hi.w = f2bf(h[3]); lo.w = f2bf(h[3] - bf2f(hi.w));
    int idx = r * 128 + (dq ^ ((r & 7) << 3));
    *(ushort4*)(AhL + idx) = hi;
    *(ushort4*)(AlL + idx) = lo;
  }
  __syncthreads();
  int lane = t & 63, wid = t >> 6;
  int rh = wid & 1, ch = wid >> 1;
  int wr = rh * 32, lrow = lane & 15, lkc = lane >> 4;
  f32x4 acc[2][4];
#pragma unroll
  for (int i = 0; i < 2; ++i)
#pragma unroll
    for (int j = 0; j < 4; ++j) acc[i][j] = (f32x4){0.f, 0.f, 0.f, 0.f};
  for (int ks = 0; ks < 4; ++ks) {
    int kb = ks * 32 + lkc * 8;
    bf16x8 ah[2], al[2];
#pragma unroll
    for (int ri = 0; ri < 2; ++ri) {
      int ar = wr + ri * 16 + lrow;
      int ai = ar * 128 + (kb ^ ((ar & 7) << 3));
      ah[ri] = *(const bf16x8*)(AhL + ai);
      al[ri] = *(const bf16x8*)(AlL + ai);
    }
    bf16x8 bh[4], bl[4];
#pragma unroll
    for (int jg = 0; jg < 4; ++jg) {
      size_t wo = (size_t)(ch * 64 + jg * 16 + lrow) * 128 + kb;
      bh[jg] = *(const bf16x8*)(Whi + wo);
      bl[jg] = *(const bf16x8*)(Wlo + wo);
    }
#pragma unroll
    for (int jg = 0; jg < 4; ++jg)
#pragma unroll
      for (int ri = 0; ri < 2; ++ri) {
        acc[ri][jg] = __builtin_amdgcn_mfma_f32_16x16x32_bf16(ah[ri], bh[jg], acc[ri][jg], 0, 0, 0);
        acc[ri][jg] = __builtin_amdgcn_mfma_f32_16x16x32_bf16(ah[ri], bl[jg], acc[ri][jg], 0, 0, 0);
        acc[ri][jg] = __builtin_amdgcn_mfma_f32_16x16x32_bf16(al[ri], bh[jg], acc[ri][jg], 0, 0, 0);
      }
  }
  float s0[4], s1[4], s2[4], s3[4];
  if (STATS) {
#pragma unroll
    for (int jg = 0; jg < 4; ++jg) { s0[jg] = 0.f; s1[jg] = 0.f; s2[jg] = 0.f; s3[jg] = 0.f; }
  }
#pragma unroll
  for (int ri = 0; ri < 2; ++ri) {
    float wsr[4], wor[4];
    if (STATS) {
#pragma unroll
      for (int q = 0; q < 4; ++q) {
        int n = rb * 64 + wr + ri * 16 + lkc * 4 + q;
        wsr[q] = (float)cnt_s[n]; wor[q] = (float)cnt_o[n];
      }
    }
#pragma unroll
    for (int jg = 0; jg < 4; ++jg) {
      int col = ch * 64 + jg * 16 + lrow;
      float bcol = bias ? bias[col] : 0.f;
#pragma unroll
      for (int q = 0; q < 4; ++q) {
        int row = wr + ri * 16 + lkc * 4 + q;
        size_t n = (size_t)rb * 64 + row;
        float vv = acc[ri][jg][q] + bcol;
        if (resid) vv += resid[n * kD + col];
        Y[n * kD + col] = vv;
        if (STATS) {
          s0[jg] += wsr[q] * vv; s1[jg] += wsr[q] * vv * vv;
          s2[jg] += wor[q] * vv; s3[jg] += wor[q] * vv * vv;
        }
      }
    }
  }
  if (STATS) {
    __syncthreads();
    float* red = (float*)AhL;  // [4 stats][8][128] = 16 KiB
    int slot = rh * 4 + lkc;
#pragma unroll
    for (int jg = 0; jg < 4; ++jg) {
      int col = ch * 64 + jg * 16 + lrow;
      red[0 * 1024 + slot * 128 + col] = s0[jg];
      red[1 * 1024 + slot * 128 + col] = s1[jg];
      red[2 * 1024 + slot * 128 + col] = s2[jg];
      red[3 * 1024 + slot * 128 + col] = s3[jg];
    }
    __syncthreads();
    if (t < 128) {
#pragma unroll
      for (int st = 0; st < 4; ++st) {
        float s = 0.f;
#pragma unroll
        for (int g = 0; g < 8; ++g) s += red[st * 1024 + g * 128 + t];
        p1out[((size_t)rb * 4 + st) * 128 + t] = s;
      }
    }
  }
}

extern "C" void kernel_launch(void* const* d_in, const int* in_sizes, int n_in,
                              void* d_out, int out_size, void* d_ws, size_t ws_size,
                              hipStream_t stream) {
  (void)in_sizes; (void)n_in; (void)out_size; (void)ws_size;
  const float* obj = (const float*)d_in[0];
  const unsigned int* ew = (const unsigned int*)d_in[1];
  const float* prm[2][8];
  for (int u = 0; u < 2; ++u)
    for (int p = 0; p < 8; ++p) prm[u][p] = (const float*)d_in[2 + u * 8 + p];
  // prm[u]: 0=g1 1=b1 2=W1 3=lb1 4=g2 5=b2 6=W2 7=lb2

  char* ws = (char*)d_ws;
  size_t off = 0;
  auto carve = [&](size_t bytes) -> char* {
    char* p = ws + off;
    off = (off + bytes + 255) & ~(size_t)255;
    return p;
  };
  int* cnt_s = (int*)carve((size_t)kN * 4);
  int* cnt_o = (int*)carve((size_t)kN * 4);
  unsigned short* Au16 = (unsigned short*)carve((size_t)kV * 16384 * 2);
  float* p1 = (float*)carve((size_t)512 * 4 * 128 * 4);
  float* p2 = (float*)carve((size_t)kV * 2 * 128 * 4);
  float* coef1 = (float*)carve(512 * 4);
  float* coef2 = (float*)carve(256 * 4);
  unsigned short *w1hi[2], *w1lo[2], *w2hi[2], *w2lo[2];
  for (int u = 0; u < 2; ++u) {
    w1hi[u] = (unsigned short*)carve((size_t)kD * 2 * kD * 2);
    w1lo[u] = (unsigned short*)carve((size_t)kD * 2 * kD * 2);
    w2hi[u] = (unsigned short*)carve((size_t)kD * kD * 2);
    w2lo[u] = (unsigned short*)carve((size_t)kD * kD * 2);
  }
  unsigned short* hsh = (unsigned short*)carve((size_t)kN * kD * 2);
  unsigned short* hsl = (unsigned short*)carve((size_t)kN * kD * 2);
  unsigned short* hoh = (unsigned short*)carve((size_t)kN * kD * 2);
  unsigned short* hol = (unsigned short*)carve((size_t)kN * kD * 2);
  float* pooled = (float*)carve((size_t)kN * kD * 4);
  float* x2 = (float*)carve((size_t)kN * kD * 4);

  k_adj<<<kV, 256, 0, stream>>>(ew, obj, cnt_s, cnt_o, Au16, p1);
  k_wsplit<<<128, 256, 0, stream>>>(prm[0][2], prm[0][6], prm[1][2], prm[1][6],
                                    w1hi[0], w1lo[0], w2hi[0], w2lo[0],
                                    w1hi[1], w1lo[1], w2hi[1], w2lo[1]);

  float* outp = (float*)d_out;
  // ---- unit 0 ----
  k_fin1<<<256, 256, 0, stream>>>(p1, prm[0][0], prm[0][1], coef1, 256);
  k_prep<<<kN / 8, 256, 0, stream>>>(obj, coef1, hsh, hsl, hoh, hol);
  k_fused1<<<kV, 1024, 0, stream>>>(hsh, hsl, hoh, hol, w1hi[0], w1lo[0], Au16,
                                    cnt_s, prm[0][3], pooled, p2);
  k_fin2<<<128, 256, 0, stream>>>(p2, prm[0][4], prm[0][5], coef2);
  k_gemm<1><<<512, 256, 0, stream>>>(pooled, w2hi[0], w2lo[0], coef2, coef2 + 128,
                                     x2, prm[0][7], nullptr, cnt_s, cnt_o, p1);
  // ---- unit 1 ----
  k_fin1<<<256, 256, 0, stream>>>(p1, prm[1][0], prm[1][1], coef1, 512);
  k_prep<<<kN / 8, 256, 0, stream>>>(x2, coef1, hsh, hsl, hoh, hol);
  k_fused1<<<kV, 1024, 0, stream>>>(hsh, hsl, hoh, hol, w1hi[1], w1lo[1], Au16,
                                    cnt_s, prm[1][3], pooled, p2);
  k_fin2<<<128, 256, 0, stream>>>(p2, prm[1][4], prm[1][5], coef2);
  k_gemm<0><<<512, 256, 0, stream>>>(pooled, w2hi[1], w2lo[1], coef2, coef2 + 128,
                                     outp, prm[1][7], obj, nullptr, nullptr, nullptr);
}

// Round 16
// 113.155 us; speedup vs baseline: 1.6490x; 1.5847x over previous
//
#include <hip/hip_runtime.h>

namespace {
constexpr int kV = 256, kO = 128, kE = 1024, kD = 128;
constexpr int kN = kV * kO;    // 32768 nodes
constexpr int kVE = kV * kE;   // 262144 edges
constexpr float kEps = 1e-5f;
}

typedef __attribute__((ext_vector_type(8))) short bf16x8;
typedef __attribute__((ext_vector_type(8))) unsigned short u16x8;
typedef __attribute__((ext_vector_type(4))) float f32x4;

__device__ __forceinline__ unsigned short f2bf(float x) {
  unsigned u = __float_as_uint(x);
  return (unsigned short)((u + 0x7FFFu + ((u >> 16) & 1u)) >> 16);
}
__device__ __forceinline__ float bf2f(unsigned short h) {
  return __uint_as_float((unsigned)h << 16);
}

// ---- K1: per-graph count matrix A[s][o] -> swizzled u16 + degrees +
// fused unit-0 BN1 stats (p1 slot v). (R13, unchanged)
__global__ __launch_bounds__(256) void k_adj(
    const unsigned int* __restrict__ ew, const float* __restrict__ X,
    int* __restrict__ cnt_s, int* __restrict__ cnt_o,
    unsigned short* __restrict__ Au16, float* __restrict__ p1) {
  __shared__ int cnt[kO * kO];  // 64 KiB (reused as float red later)
  __shared__ int degS[kO], degO[kO];
  __shared__ int anyodd;
  int v = blockIdx.x, t = threadIdx.x;
  if (t == 0) anyodd = 0;
  for (int i = t; i < kO * kO; i += 256) cnt[i] = 0;
  __syncthreads();
  int base = v * 3072, loc = 0;
  for (int i = t; i < 3072; i += 256) {
    int g = base + i;
    if ((g & 1) && ew[g] != 0u) loc = 1;
  }
  if (loc) atomicOr(&anyodd, 1);
  __syncthreads();
  bool is64 = (anyodd == 0);
  for (int e = t; e < kE; e += 256) {
    long long eb = (long long)(v * kE + e) * 3;
    unsigned s, o;
    if (is64) { s = ew[2 * eb]; o = ew[2 * (eb + 2)]; }
    else      { s = ew[eb];     o = ew[eb + 2]; }
    s &= 127u; o &= 127u;
    atomicAdd(&cnt[s * kO + o], 1);
  }
  __syncthreads();
  unsigned int* A32 = (unsigned int*)(Au16 + (size_t)v * 16384);
  for (int i2 = t; i2 < 8192; i2 += 256) {
    int i = 2 * i2;
    int row = i >> 7, k = i & 127, kg = k >> 3;
    int j = row * 128 + ((kg ^ (row & 7)) << 3) + (k & 7);
    unsigned lo = (unsigned)cnt[i], hi = (unsigned)cnt[i + 1];
    A32[j >> 1] = lo | (hi << 16);
  }
  if (t < kO) {
    int s = 0;
    for (int c = 0; c < kO; ++c) s += cnt[t * kO + ((c + t) & 127)];
    degS[t] = s;
    cnt_s[v * kO + t] = s;
  } else {
    int tc = t - kO;
    int s = 0;
    for (int r = 0; r < kO; ++r) s += cnt[((r + tc) & 127) * kO + tc];
    degO[tc] = s;
    cnt_o[v * kO + tc] = s;
  }
  __syncthreads();
  int dq = (t & 31) * 4, rg = t >> 5;
  float acc[4][4];
#pragma unroll
  for (int a = 0; a < 4; ++a)
#pragma unroll
    for (int j = 0; j < 4; ++j) acc[a][j] = 0.f;
  for (int k = 0; k < 16; ++k) {
    int row = rg + k * 8;
    float4 xv = *(const float4*)(X + ((size_t)v * kO + row) * kD + dq);
    float wsv = (float)degS[row], wov = (float)degO[row];
    float xs[4] = {xv.x, xv.y, xv.z, xv.w};
#pragma unroll
    for (int j = 0; j < 4; ++j) {
      acc[0][j] += wsv * xs[j];
      acc[1][j] += wsv * xs[j] * xs[j];
      acc[2][j] += wov * xs[j];
      acc[3][j] += wov * xs[j] * xs[j];
    }
  }
  float* red = (float*)cnt;
  for (int st = 0; st < 4; ++st) {
    __syncthreads();
#pragma unroll
    for (int j = 0; j < 4; ++j) red[rg * 128 + dq + j] = acc[st][j];
    __syncthreads();
    if (t < 128) {
      float s = 0.f;
#pragma unroll
      for (int g = 0; g < 8; ++g) s += red[g * 128 + t];
      p1[((size_t)v * 4 + st) * 128 + t] = s;
    }
  }
}

// ---- K1b: split weights. W1 -> swizzled LDS image (4 x 32KB regions:
// sH,sL,oH,oL; pos = j*128 + (kk ^ ((j&7)<<3))). W2 -> linear hi/lo.
__global__ __launch_bounds__(256) void k_wsplit(
    const float* __restrict__ w1u0, const float* __restrict__ w2u0,
    const float* __restrict__ w1u1, const float* __restrict__ w2u1,
    unsigned short* __restrict__ img0,
    unsigned short* __restrict__ w2h0, unsigned short* __restrict__ w2l0,
    unsigned short* __restrict__ img1,
    unsigned short* __restrict__ w2h1, unsigned short* __restrict__ w2l1) {
  const float* w1s[2] = {w1u0, w1u1};
  const float* w2s[2] = {w2u0, w2u1};
  unsigned short* img[2] = {img0, img1};
  unsigned short* w2h[2] = {w2h0, w2h1};
  unsigned short* w2l[2] = {w2l0, w2l1};
  int i0 = blockIdx.x * 256 + threadIdx.x, stride = gridDim.x * 256;
#pragma unroll
  for (int u = 0; u < 2; ++u) {
    for (int i = i0; i < kD * 2 * kD; i += stride) {
      int j = i >> 8, k = i & 255;
      int m = k >> 7, kk = k & 127;
      int pos = j * 128 + (kk ^ ((j & 7) << 3));
      float x = w1s[u][i];
      unsigned short hb = f2bf(x);
      img[u][(m * 2 + 0) * 16384 + pos] = hb;
      img[u][(m * 2 + 1) * 16384 + pos] = f2bf(x - bf2f(hb));
    }
    for (int i = i0; i < kD * kD; i += stride) {
      float x = w2s[u][i];
      unsigned short hb = f2bf(x);
      w2h[u][i] = hb;
      w2l[u][i] = f2bf(x - bf2f(hb));
    }
  }
}

// ---- K3: finalize BN1 coeffs — 256 blocks (one per column), nslots partials
__global__ __launch_bounds__(256) void k_fin1(
    const float* __restrict__ p1, const float* __restrict__ g1,
    const float* __restrict__ b1, float* __restrict__ coef, int nslots) {
  __shared__ double sS[256], sQ[256];
  int c = blockIdx.x, t = threadIdx.x;
  int half = c >> 7, d = c & 127;
  double S = 0.0, Q = 0.0;
  for (int b = t; b < nslots; b += 256) {
    S += (double)p1[((size_t)b * 4 + half * 2 + 0) * 128 + d];
    Q += (double)p1[((size_t)b * 4 + half * 2 + 1) * 128 + d];
  }
  sS[t] = S; sQ[t] = Q;
  __syncthreads();
  for (int s = 128; s > 0; s >>= 1) {
    if (t < s) { sS[t] += sS[t + s]; sQ[t] += sQ[t + s]; }
    __syncthreads();
  }
  if (t == 0) {
    double m = sS[0] / (double)kVE;
    double var = sQ[0] / (double)kVE - m * m;
    float a = g1[c] / sqrtf((float)var + kEps);
    float beta = b1[c] - (float)m * a;
    coef[half * 256 + d] = a;
    coef[half * 256 + 128 + d] = beta;
  }
}

// ---- K4: FUSED per-graph kernel, 512 threads (8 waves, 2/SIMD), 128 KiB LDS.
// W1 image async-staged to LDS at entry; A-operands (hs/ho) computed per-lane
// into REGISTERS (no staging barrier); adjacency A in regs. MFMA loops are
// LDS/register-only — zero global loads on the critical path.
__global__ __launch_bounds__(512, 2) void k_fused1(
    const float* __restrict__ X, const unsigned short* __restrict__ w1img,
    const float* __restrict__ coef, const unsigned short* __restrict__ Au16,
    const int* __restrict__ cnt_s, const float* __restrict__ lb1,
    float* __restrict__ pooled, float* __restrict__ p2) {
  __shared__ __align__(16) unsigned short Wl[4][16384];  // sH,sL,oH,oL -> yoT/red
  int t = threadIdx.x, v = blockIdx.x;
  int lane = t & 63, wid = t >> 6;  // 8 waves, 16 rows each
  int wr = wid * 16, lrow = lane & 15, lkc = lane >> 4;
  int arow = wr + lrow;
  // ---- entry: async stage W image (4 x 32 KB, linear) ----
#pragma unroll
  for (int a = 0; a < 4; ++a)
#pragma unroll
    for (int i = 0; i < 4; ++i)
      __builtin_amdgcn_global_load_lds(
          (const unsigned int*)((const char*)(w1img + a * 16384) +
                                wid * 4096 + i * 1024 + lane * 16),
          (unsigned int*)((char*)Wl[a] + wid * 4096 + i * 1024), 16, 0, 0);
  // ---- adjacency prefetch (phase-D fragment mapping) ----
  u16x8 au[4];
#pragma unroll
  for (int ks = 0; ks < 4; ++ks) {
    int kg = ks * 4 + lkc;
    au[ks] = *(const u16x8*)(Au16 + (size_t)v * 16384 + arow * 128 +
                             ((kg ^ (arow & 7)) << 3));
  }
  // ---- per-lane transform: X row -> hs/ho bf16 hi/lo fragments in regs ----
  bf16x8 hsH[4], hsL[4], hoH[4], hoL[4];
#pragma unroll
  for (int ks = 0; ks < 4; ++ks) {
    int kb = ks * 32 + lkc * 8;
    float4 x0 = *(const float4*)(X + ((size_t)v * kO + arow) * kD + kb);
    float4 x1 = *(const float4*)(X + ((size_t)v * kO + arow) * kD + kb + 4);
    float4 aS0 = *(const float4*)(coef + kb),       aS1 = *(const float4*)(coef + kb + 4);
    float4 bS0 = *(const float4*)(coef + 128 + kb), bS1 = *(const float4*)(coef + 128 + kb + 4);
    float4 aO0 = *(const float4*)(coef + 256 + kb), aO1 = *(const float4*)(coef + 256 + kb + 4);
    float4 bO0 = *(const float4*)(coef + 384 + kb), bO1 = *(const float4*)(coef + 384 + kb + 4);
    float xs[8] = {x0.x, x0.y, x0.z, x0.w, x1.x, x1.y, x1.z, x1.w};
    float as[8] = {aS0.x, aS0.y, aS0.z, aS0.w, aS1.x, aS1.y, aS1.z, aS1.w};
    float bs[8] = {bS0.x, bS0.y, bS0.z, bS0.w, bS1.x, bS1.y, bS1.z, bS1.w};
    float ao[8] = {aO0.x, aO0.y, aO0.z, aO0.w, aO1.x, aO1.y, aO1.z, aO1.w};
    float bo[8] = {bO0.x, bO0.y, bO0.z, bO0.w, bO1.x, bO1.y, bO1.z, bO1.w};
#pragma unroll
    for (int e = 0; e < 8; ++e) {
      float hs = fmaxf(as[e] * xs[e] + bs[e], 0.f);
      float ho = fmaxf(ao[e] * xs[e] + bo[e], 0.f);
      unsigned short h1 = f2bf(hs);
      hsH[ks][e] = (short)h1;
      hsL[ks][e] = (short)f2bf(hs - bf2f(h1));
      unsigned short h2 = f2bf(ho);
      hoH[ks][e] = (short)h2;
      hoL[ks][e] = (short)f2bf(ho - bf2f(h2));
    }
  }
  __syncthreads();  // drain W staging
  // ---- Phase B: ys + yo GEMMs (A in regs, W in LDS) ----
  f32x4 accS[8], accO[8];
#pragma unroll
  for (int j = 0; j < 8; ++j) {
    accS[j] = (f32x4){0.f, 0.f, 0.f, 0.f};
    accO[j] = (f32x4){0.f, 0.f, 0.f, 0.f};
  }
#pragma unroll
  for (int ks = 0; ks < 4; ++ks) {
    int kb = ks * 32 + lkc * 8;
#pragma unroll
    for (int jg = 0; jg < 8; ++jg) {
      int j = jg * 16 + lrow;
      int idx = j * 128 + (kb ^ ((j & 7) << 3));
      bf16x8 bsh = *(const bf16x8*)(&Wl[0][idx]);
      bf16x8 bsl = *(const bf16x8*)(&Wl[1][idx]);
      bf16x8 boh = *(const bf16x8*)(&Wl[2][idx]);
      bf16x8 bol = *(const bf16x8*)(&Wl[3][idx]);
      accS[jg] = __builtin_amdgcn_mfma_f32_16x16x32_bf16(hsH[ks], bsh, accS[jg], 0, 0, 0);
      accS[jg] = __builtin_amdgcn_mfma_f32_16x16x32_bf16(hsH[ks], bsl, accS[jg], 0, 0, 0);
      accS[jg] = __builtin_amdgcn_mfma_f32_16x16x32_bf16(hsL[ks], bsh, accS[jg], 0, 0, 0);
      accO[jg] = __builtin_amdgcn_mfma_f32_16x16x32_bf16(hoH[ks], boh, accO[jg], 0, 0, 0);
      accO[jg] = __builtin_amdgcn_mfma_f32_16x16x32_bf16(hoH[ks], bol, accO[jg], 0, 0, 0);
      accO[jg] = __builtin_amdgcn_mfma_f32_16x16x32_bf16(hoL[ks], boh, accO[jg], 0, 0, 0);
    }
  }
  __syncthreads();  // W consumed
  // ---- Phase C: transpose accO -> yoT into Wl[0]/Wl[1] (swizzle <<3) ----
#pragma unroll
  for (int jg = 0; jg < 8; ++jg) {
    int d = jg * 16 + lrow;
#pragma unroll
    for (int q = 0; q < 4; ++q) {
      int o = wr + lkc * 4 + q;
      int addr = d * 128 + (o ^ ((d & 7) << 3));
      float vv = accO[jg][q];
      unsigned short h = f2bf(vv);
      Wl[0][addr] = h;
      Wl[1][addr] = f2bf(vv - bf2f(h));
    }
  }
  __syncthreads();
  // ---- Phase D: pool GEMM: A (regs u16 -> hi/lo) x yoT (LDS) ----
  f32x4 accP[8];
#pragma unroll
  for (int j = 0; j < 8; ++j) accP[j] = (f32x4){0.f, 0.f, 0.f, 0.f};
#pragma unroll
  for (int ks = 0; ks < 4; ++ks) {
    int kb = ks * 32 + lkc * 8;
    bf16x8 pah, pal;
#pragma unroll
    for (int e = 0; e < 8; ++e) {
      float c = (float)au[ks][e];
      unsigned short hb = f2bf(c);
      pah[e] = (short)hb;
      pal[e] = (short)f2bf(c - bf2f(hb));
    }
#pragma unroll
    for (int jg = 0; jg < 8; ++jg) {
      int d = jg * 16 + lrow;
      int qi = d * 128 + (kb ^ ((d & 7) << 3));
      bf16x8 qh = *(const bf16x8*)(&Wl[0][qi]), ql = *(const bf16x8*)(&Wl[1][qi]);
      accP[jg] = __builtin_amdgcn_mfma_f32_16x16x32_bf16(pah, qh, accP[jg], 0, 0, 0);
      accP[jg] = __builtin_amdgcn_mfma_f32_16x16x32_bf16(pah, ql, accP[jg], 0, 0, 0);
      accP[jg] = __builtin_amdgcn_mfma_f32_16x16x32_bf16(pal, qh, accP[jg], 0, 0, 0);
    }
  }
  // ---- Phase E: pooled + BN2 partials (red scratch in Wl[2]) ----
  float lb[8];
#pragma unroll
  for (int jg = 0; jg < 8; ++jg) lb[jg] = lb1[jg * 16 + lrow];
  float sm[8], sq[8];
#pragma unroll
  for (int jg = 0; jg < 8; ++jg) { sm[jg] = 0.f; sq[jg] = 0.f; }
#pragma unroll
  for (int q = 0; q < 4; ++q) {
    int row = wr + lkc * 4 + q;
    size_t n = (size_t)v * kO + row;
    int cnt = cnt_s[n];
    float inv = (cnt > 0) ? 1.f / (float)cnt : 0.f;
#pragma unroll
    for (int jg = 0; jg < 8; ++jg) {
      int col = jg * 16 + lrow;
      float pv = 0.f;
      if (cnt > 0) pv = accS[jg][q] + lb[jg] + accP[jg][q] * inv;
      pooled[n * kD + col] = pv;
      sm[jg] += pv; sq[jg] += pv * pv;
    }
  }
  float* red = (float*)Wl[2];  // [32][128] f32 = 16 KiB
  int slot = wid * 4 + lkc;    // 0..31
#pragma unroll
  for (int jg = 0; jg < 8; ++jg) red[slot * 128 + jg * 16 + lrow] = sm[jg];
  __syncthreads();
  if (t < 128) {
    float s = 0.f;
#pragma unroll
    for (int g = 0; g < 32; ++g) s += red[g * 128 + t];
    p2[((size_t)v * 2 + 0) * 128 + t] = s;
  }
  __syncthreads();
#pragma unroll
  for (int jg = 0; jg < 8; ++jg) red[slot * 128 + jg * 16 + lrow] = sq[jg];
  __syncthreads();
  if (t < 128) {
    float s = 0.f;
#pragma unroll
    for (int g = 0; g < 32; ++g) s += red[g * 128 + t];
    p2[((size_t)v * 2 + 1) * 128 + t] = s;
  }
}

// ---- K6: finalize BN2 coeffs — 128 blocks (one per column), 256 partials ----
__global__ __launch_bounds__(256) void k_fin2(
    const float* __restrict__ p2, const float* __restrict__ g2,
    const float* __restrict__ b2, float* __restrict__ coef2) {
  __shared__ double sS[256], sQ[256];
  int d = blockIdx.x, t = threadIdx.x;
  double S = (double)p2[((size_t)t * 2 + 0) * 128 + d];
  double Q = (double)p2[((size_t)t * 2 + 1) * 128 + d];
  sS[t] = S; sQ[t] = Q;
  __syncthreads();
  for (int s = 128; s > 0; s >>= 1) {
    if (t < s) { sS[t] += sS[t + s]; sQ[t] += sQ[t + s]; }
    __syncthreads();
  }
  if (t == 0) {
    double m = sS[0] / (double)kN, var = sQ[0] / (double)kN - m * m;
    float a = g2[d] / sqrtf((float)var + kEps);
    float beta = b2[d] - (float)m * a;
    coef2[d] = a; coef2[128 + d] = beta;
  }
}

// ---- K7: W2 GEMM, 64-row x 128-col tiles, 512 blocks (R13, unchanged) ----
template <int STATS>
__global__ __launch_bounds__(256, 2) void k_gemm(
    const float* __restrict__ X,
    const unsigned short* __restrict__ Whi, const unsigned short* __restrict__ Wlo,
    const float* __restrict__ coefA, const float* __restrict__ coefB,
    float* __restrict__ Y, const float* __restrict__ bias, const float* __restrict__ resid,
    const int* __restrict__ cnt_s, const int* __restrict__ cnt_o,
    float* __restrict__ p1out) {
  __shared__ __align__(16) unsigned short AhL[8192], AlL[8192];
  int t = threadIdx.x, rb = blockIdx.x;
  int dq = (t & 31) * 4, rg = t >> 5;
  float4 av = *(const float4*)(coefA + dq);
  float4 bv = *(const float4*)(coefB + dq);
  for (int k = 0; k < 8; ++k) {
    int r = rg + k * 8;
    float4 xv = *(const float4*)(X + ((size_t)rb * 64 + r) * kD + dq);
    float h[4] = {fmaxf(av.x * xv.x + bv.x, 0.f), fmaxf(av.y * xv.y + bv.y, 0.f),
                  fmaxf(av.z * xv.z + bv.z, 0.f), fmaxf(av.w * xv.w + bv.w, 0.f)};
    ushort4 hi, lo;
    hi.x = f2bf(h[0]); lo.x = f2bf(h[0] - bf2f(hi.x));
    hi.y = f2bf(h[1]); lo.y = f2bf(h[1] - bf2f(hi.y));
    hi.z = f2bf(h[2]); lo.z = f2bf(h[2] - bf2f(hi.z));
    hi.w = f2bf(h[3]); lo.w = f2bf(h[3] - bf2f(hi.w));
    int idx = r * 128 + (dq ^ ((r & 7) << 3));
    *(ushort4*)(AhL + idx) = hi;
    *(ushort4*)(AlL + idx) = lo;
  }
  __syncthreads();
  int lane = t & 63, wid = t >> 6;
  int rh = wid & 1, ch = wid >> 1;
  int wr = rh * 32, lrow = lane & 15, lkc = lane >> 4;
  f32x4 acc[2][4];
#pragma unroll
  for (int i = 0; i < 2; ++i)
#pragma unroll
    for (int j = 0; j < 4; ++j) acc[i][j] = (f32x4){0.f, 0.f, 0.f, 0.f};
  for (int ks = 0; ks < 4; ++ks) {
    int kb = ks * 32 + lkc * 8;
    bf16x8 ah[2], al[2];
#pragma unroll
    for (int ri = 0; ri < 2; ++ri) {
      int ar = wr + ri * 16 + lrow;
      int ai = ar * 128 + (kb ^ ((ar & 7) << 3));
      ah[ri] = *(const bf16x8*)(AhL + ai);
      al[ri] = *(const bf16x8*)(AlL + ai);
    }
    bf16x8 bh[4], bl[4];
#pragma unroll
    for (int jg = 0; jg < 4; ++jg) {
      size_t wo = (size_t)(ch * 64 + jg * 16 + lrow) * 128 + kb;
      bh[jg] = *(const bf16x8*)(Whi + wo);
      bl[jg] = *(const bf16x8*)(Wlo + wo);
    }
#pragma unroll
    for (int jg = 0; jg < 4; ++jg)
#pragma unroll
      for (int ri = 0; ri < 2; ++ri) {
        acc[ri][jg] = __builtin_amdgcn_mfma_f32_16x16x32_bf16(ah[ri], bh[jg], acc[ri][jg], 0, 0, 0);
        acc[ri][jg] = __builtin_amdgcn_mfma_f32_16x16x32_bf16(ah[ri], bl[jg], acc[ri][jg], 0, 0, 0);
        acc[ri][jg] = __builtin_amdgcn_mfma_f32_16x16x32_bf16(al[ri], bh[jg], acc[ri][jg], 0, 0, 0);
      }
  }
  float s0[4], s1[4], s2[4], s3[4];
  if (STATS) {
#pragma unroll
    for (int jg = 0; jg < 4; ++jg) { s0[jg] = 0.f; s1[jg] = 0.f; s2[jg] = 0.f; s3[jg] = 0.f; }
  }
#pragma unroll
  for (int ri = 0; ri < 2; ++ri) {
    float wsr[4], wor[4];
    if (STATS) {
#pragma unroll
      for (int q = 0; q < 4; ++q) {
        int n = rb * 64 + wr + ri * 16 + lkc * 4 + q;
        wsr[q] = (float)cnt_s[n]; wor[q] = (float)cnt_o[n];
      }
    }
#pragma unroll
    for (int jg = 0; jg < 4; ++jg) {
      int col = ch * 64 + jg * 16 + lrow;
      float bcol = bias ? bias[col] : 0.f;
#pragma unroll
      for (int q = 0; q < 4; ++q) {
        int row = wr + ri * 16 + lkc * 4 + q;
        size_t n = (size_t)rb * 64 + row;
        float vv = acc[ri][jg][q] + bcol;
        if (resid) vv += resid[n * kD + col];
        Y[n * kD + col] = vv;
        if (STATS) {
          s0[jg] += wsr[q] * vv; s1[jg] += wsr[q] * vv * vv;
          s2[jg] += wor[q] * vv; s3[jg] += wor[q] * vv * vv;
        }
      }
    }
  }
  if (STATS) {
    __syncthreads();
    float* red = (float*)AhL;  // [4 stats][8][128] = 16 KiB
    int slot = rh * 4 + lkc;
#pragma unroll
    for (int jg = 0; jg < 4; ++jg) {
      int col = ch * 64 + jg * 16 + lrow;
      red[0 * 1024 + slot * 128 + col] = s0[jg];
      red[1 * 1024 + slot * 128 + col] = s1[jg];
      red[2 * 1024 + slot * 128 + col] = s2[jg];
      red[3 * 1024 + slot * 128 + col] = s3[jg];
    }
    __syncthreads();
    if (t < 128) {
#pragma unroll
      for (int st = 0; st < 4; ++st) {
        float s = 0.f;
#pragma unroll
        for (int g = 0; g < 8; ++g) s += red[st * 1024 + g * 128 + t];
        p1out[((size_t)rb * 4 + st) * 128 + t] = s;
      }
    }
  }
}

extern "C" void kernel_launch(void* const* d_in, const int* in_sizes, int n_in,
                              void* d_out, int out_size, void* d_ws, size_t ws_size,
                              hipStream_t stream) {
  (void)in_sizes; (void)n_in; (void)out_size; (void)ws_size;
  const float* obj = (const float*)d_in[0];
  const unsigned int* ew = (const unsigned int*)d_in[1];
  const float* prm[2][8];
  for (int u = 0; u < 2; ++u)
    for (int p = 0; p < 8; ++p) prm[u][p] = (const float*)d_in[2 + u * 8 + p];
  // prm[u]: 0=g1 1=b1 2=W1 3=lb1 4=g2 5=b2 6=W2 7=lb2

  char* ws = (char*)d_ws;
  size_t off = 0;
  auto carve = [&](size_t bytes) -> char* {
    char* p = ws + off;
    off = (off + bytes + 255) & ~(size_t)255;
    return p;
  };
  int* cnt_s = (int*)carve((size_t)kN * 4);
  int* cnt_o = (int*)carve((size_t)kN * 4);
  unsigned short* Au16 = (unsigned short*)carve((size_t)kV * 16384 * 2);
  float* p1 = (float*)carve((size_t)512 * 4 * 128 * 4);
  float* p2 = (float*)carve((size_t)kV * 2 * 128 * 4);
  float* coef1 = (float*)carve(512 * 4);
  float* coef2 = (float*)carve(256 * 4);
  unsigned short *w1img[2], *w2hi[2], *w2lo[2];
  for (int u = 0; u < 2; ++u) {
    w1img[u] = (unsigned short*)carve((size_t)4 * 16384 * 2);  // 128 KB
    w2hi[u] = (unsigned short*)carve((size_t)kD * kD * 2);
    w2lo[u] = (unsigned short*)carve((size_t)kD * kD * 2);
  }
  float* pooled = (float*)carve((size_t)kN * kD * 4);
  float* x2 = (float*)carve((size_t)kN * kD * 4);

  k_adj<<<kV, 256, 0, stream>>>(ew, obj, cnt_s, cnt_o, Au16, p1);
  k_wsplit<<<128, 256, 0, stream>>>(prm[0][2], prm[0][6], prm[1][2], prm[1][6],
                                    w1img[0], w2hi[0], w2lo[0],
                                    w1img[1], w2hi[1], w2lo[1]);

  float* outp = (float*)d_out;
  // ---- unit 0 ----
  k_fin1<<<256, 256, 0, stream>>>(p1, prm[0][0], prm[0][1], coef1, 256);
  k_fused1<<<kV, 512, 0, stream>>>(obj, w1img[0], coef1, Au16,
                                   cnt_s, prm[0][3], pooled, p2);
  k_fin2<<<128, 256, 0, stream>>>(p2, prm[0][4], prm[0][5], coef2);
  k_gemm<1><<<512, 256, 0, stream>>>(pooled, w2hi[0], w2lo[0], coef2, coef2 + 128,
                                     x2, prm[0][7], nullptr, cnt_s, cnt_o, p1);
  // ---- unit 1 ----
  k_fin1<<<256, 256, 0, stream>>>(p1, prm[1][0], prm[1][1], coef1, 512);
  k_fused1<<<kV, 512, 0, stream>>>(x2, w1img[1], coef1, Au16,
                                   cnt_s, prm[1][3], pooled, p2);
  k_fin2<<<128, 256, 0, stream>>>(p2, prm[1][4], prm[1][5], coef2);
  k_gemm<0><<<512, 256, 0, stream>>>(pooled, w2hi[1], w2lo[1], coef2, coef2 + 128,
                                     outp, prm[1][7], obj, nullptr, nullptr, nullptr);
}

// Round 17
// 104.927 us; speedup vs baseline: 1.7783x; 1.0784x over previous
//
#include <hip/hip_runtime.h>

namespace {
constexpr int kV = 256, kO = 128, kE = 1024, kD = 128;
constexpr int kN = kV * kO;    // 32768 nodes
constexpr int kVE = kV * kE;   // 262144 edges
constexpr float kEps = 1e-5f;
}

typedef __attribute__((ext_vector_type(8))) short bf16x8;
typedef __attribute__((ext_vector_type(8))) unsigned short u16x8;
typedef __attribute__((ext_vector_type(4))) float f32x4;

__device__ __forceinline__ unsigned short f2bf(float x) {
  unsigned u = __float_as_uint(x);
  return (unsigned short)((u + 0x7FFFu + ((u >> 16) & 1u)) >> 16);
}
__device__ __forceinline__ float bf2f(unsigned short h) {
  return __uint_as_float((unsigned)h << 16);
}

// ---- K1: per-graph count matrix A[s][o] -> swizzled u16 + degrees +
// fused unit-0 BN1 stats (p1 slot v). (R16, unchanged)
__global__ __launch_bounds__(256) void k_adj(
    const unsigned int* __restrict__ ew, const float* __restrict__ X,
    int* __restrict__ cnt_s, int* __restrict__ cnt_o,
    unsigned short* __restrict__ Au16, float* __restrict__ p1) {
  __shared__ int cnt[kO * kO];  // 64 KiB (reused as float red later)
  __shared__ int degS[kO], degO[kO];
  __shared__ int anyodd;
  int v = blockIdx.x, t = threadIdx.x;
  if (t == 0) anyodd = 0;
  for (int i = t; i < kO * kO; i += 256) cnt[i] = 0;
  __syncthreads();
  int base = v * 3072, loc = 0;
  for (int i = t; i < 3072; i += 256) {
    int g = base + i;
    if ((g & 1) && ew[g] != 0u) loc = 1;
  }
  if (loc) atomicOr(&anyodd, 1);
  __syncthreads();
  bool is64 = (anyodd == 0);
  for (int e = t; e < kE; e += 256) {
    long long eb = (long long)(v * kE + e) * 3;
    unsigned s, o;
    if (is64) { s = ew[2 * eb]; o = ew[2 * (eb + 2)]; }
    else      { s = ew[eb];     o = ew[eb + 2]; }
    s &= 127u; o &= 127u;
    atomicAdd(&cnt[s * kO + o], 1);
  }
  __syncthreads();
  unsigned int* A32 = (unsigned int*)(Au16 + (size_t)v * 16384);
  for (int i2 = t; i2 < 8192; i2 += 256) {
    int i = 2 * i2;
    int row = i >> 7, k = i & 127, kg = k >> 3;
    int j = row * 128 + ((kg ^ (row & 7)) << 3) + (k & 7);
    unsigned lo = (unsigned)cnt[i], hi = (unsigned)cnt[i + 1];
    A32[j >> 1] = lo | (hi << 16);
  }
  if (t < kO) {
    int s = 0;
    for (int c = 0; c < kO; ++c) s += cnt[t * kO + ((c + t) & 127)];
    degS[t] = s;
    cnt_s[v * kO + t] = s;
  } else {
    int tc = t - kO;
    int s = 0;
    for (int r = 0; r < kO; ++r) s += cnt[((r + tc) & 127) * kO + tc];
    degO[tc] = s;
    cnt_o[v * kO + tc] = s;
  }
  __syncthreads();
  int dq = (t & 31) * 4, rg = t >> 5;
  float acc[4][4];
#pragma unroll
  for (int a = 0; a < 4; ++a)
#pragma unroll
    for (int j = 0; j < 4; ++j) acc[a][j] = 0.f;
  for (int k = 0; k < 16; ++k) {
    int row = rg + k * 8;
    float4 xv = *(const float4*)(X + ((size_t)v * kO + row) * kD + dq);
    float wsv = (float)degS[row], wov = (float)degO[row];
    float xs[4] = {xv.x, xv.y, xv.z, xv.w};
#pragma unroll
    for (int j = 0; j < 4; ++j) {
      acc[0][j] += wsv * xs[j];
      acc[1][j] += wsv * xs[j] * xs[j];
      acc[2][j] += wov * xs[j];
      acc[3][j] += wov * xs[j] * xs[j];
    }
  }
  float* red = (float*)cnt;
  for (int st = 0; st < 4; ++st) {
    __syncthreads();
#pragma unroll
    for (int j = 0; j < 4; ++j) red[rg * 128 + dq + j] = acc[st][j];
    __syncthreads();
    if (t < 128) {
      float s = 0.f;
#pragma unroll
      for (int g = 0; g < 8; ++g) s += red[g * 128 + t];
      p1[((size_t)v * 4 + st) * 128 + t] = s;
    }
  }
}

// ---- K1b: split weights. W1 -> swizzled LDS image (4 x 32KB: sH,sL,oH,oL);
// W2 -> swizzled LDS image (2 x 32KB: hi,lo). pos = j*128 + (kk ^ ((j&7)<<3)).
__global__ __launch_bounds__(256) void k_wsplit(
    const float* __restrict__ w1u0, const float* __restrict__ w2u0,
    const float* __restrict__ w1u1, const float* __restrict__ w2u1,
    unsigned short* __restrict__ img0, unsigned short* __restrict__ w2img0,
    unsigned short* __restrict__ img1, unsigned short* __restrict__ w2img1) {
  const float* w1s[2] = {w1u0, w1u1};
  const float* w2s[2] = {w2u0, w2u1};
  unsigned short* img[2] = {img0, img1};
  unsigned short* w2i[2] = {w2img0, w2img1};
  int i0 = blockIdx.x * 256 + threadIdx.x, stride = gridDim.x * 256;
#pragma unroll
  for (int u = 0; u < 2; ++u) {
    for (int i = i0; i < kD * 2 * kD; i += stride) {
      int j = i >> 8, k = i & 255;
      int m = k >> 7, kk = k & 127;
      int pos = j * 128 + (kk ^ ((j & 7) << 3));
      float x = w1s[u][i];
      unsigned short hb = f2bf(x);
      img[u][(m * 2 + 0) * 16384 + pos] = hb;
      img[u][(m * 2 + 1) * 16384 + pos] = f2bf(x - bf2f(hb));
    }
    for (int i = i0; i < kD * kD; i += stride) {
      int j = i >> 7, kk = i & 127;
      int pos = j * 128 + (kk ^ ((j & 7) << 3));
      float x = w2s[u][i];
      unsigned short hb = f2bf(x);
      w2i[u][pos] = hb;
      w2i[u][16384 + pos] = f2bf(x - bf2f(hb));
    }
  }
}

// ---- K3: finalize BN1 coeffs — 256 blocks (one per column), nslots partials
__global__ __launch_bounds__(256) void k_fin1(
    const float* __restrict__ p1, const float* __restrict__ g1,
    const float* __restrict__ b1, float* __restrict__ coef, int nslots) {
  __shared__ double sS[256], sQ[256];
  int c = blockIdx.x, t = threadIdx.x;
  int half = c >> 7, d = c & 127;
  double S = 0.0, Q = 0.0;
  for (int b = t; b < nslots; b += 256) {
    S += (double)p1[((size_t)b * 4 + half * 2 + 0) * 128 + d];
    Q += (double)p1[((size_t)b * 4 + half * 2 + 1) * 128 + d];
  }
  sS[t] = S; sQ[t] = Q;
  __syncthreads();
  for (int s = 128; s > 0; s >>= 1) {
    if (t < s) { sS[t] += sS[t + s]; sQ[t] += sQ[t + s]; }
    __syncthreads();
  }
  if (t == 0) {
    double m = sS[0] / (double)kVE;
    double var = sQ[0] / (double)kVE - m * m;
    float a = g1[c] / sqrtf((float)var + kEps);
    float beta = b1[c] - (float)m * a;
    coef[half * 256 + d] = a;
    coef[half * 256 + 128 + d] = beta;
  }
}

// ---- K4: FUSED per-graph kernel (R16, unchanged — the 113 µs winner) ----
__global__ __launch_bounds__(512, 2) void k_fused1(
    const float* __restrict__ X, const unsigned short* __restrict__ w1img,
    const float* __restrict__ coef, const unsigned short* __restrict__ Au16,
    const int* __restrict__ cnt_s, const float* __restrict__ lb1,
    float* __restrict__ pooled, float* __restrict__ p2) {
  __shared__ __align__(16) unsigned short Wl[4][16384];  // sH,sL,oH,oL -> yoT/red
  int t = threadIdx.x, v = blockIdx.x;
  int lane = t & 63, wid = t >> 6;  // 8 waves, 16 rows each
  int wr = wid * 16, lrow = lane & 15, lkc = lane >> 4;
  int arow = wr + lrow;
#pragma unroll
  for (int a = 0; a < 4; ++a)
#pragma unroll
    for (int i = 0; i < 4; ++i)
      __builtin_amdgcn_global_load_lds(
          (const unsigned int*)((const char*)(w1img + a * 16384) +
                                wid * 4096 + i * 1024 + lane * 16),
          (unsigned int*)((char*)Wl[a] + wid * 4096 + i * 1024), 16, 0, 0);
  u16x8 au[4];
#pragma unroll
  for (int ks = 0; ks < 4; ++ks) {
    int kg = ks * 4 + lkc;
    au[ks] = *(const u16x8*)(Au16 + (size_t)v * 16384 + arow * 128 +
                             ((kg ^ (arow & 7)) << 3));
  }
  bf16x8 hsH[4], hsL[4], hoH[4], hoL[4];
#pragma unroll
  for (int ks = 0; ks < 4; ++ks) {
    int kb = ks * 32 + lkc * 8;
    float4 x0 = *(const float4*)(X + ((size_t)v * kO + arow) * kD + kb);
    float4 x1 = *(const float4*)(X + ((size_t)v * kO + arow) * kD + kb + 4);
    float4 aS0 = *(const float4*)(coef + kb),       aS1 = *(const float4*)(coef + kb + 4);
    float4 bS0 = *(const float4*)(coef + 128 + kb), bS1 = *(const float4*)(coef + 128 + kb + 4);
    float4 aO0 = *(const float4*)(coef + 256 + kb), aO1 = *(const float4*)(coef + 256 + kb + 4);
    float4 bO0 = *(const float4*)(coef + 384 + kb), bO1 = *(const float4*)(coef + 384 + kb + 4);
    float xs[8] = {x0.x, x0.y, x0.z, x0.w, x1.x, x1.y, x1.z, x1.w};
    float as[8] = {aS0.x, aS0.y, aS0.z, aS0.w, aS1.x, aS1.y, aS1.z, aS1.w};
    float bs[8] = {bS0.x, bS0.y, bS0.z, bS0.w, bS1.x, bS1.y, bS1.z, bS1.w};
    float ao[8] = {aO0.x, aO0.y, aO0.z, aO0.w, aO1.x, aO1.y, aO1.z, aO1.w};
    float bo[8] = {bO0.x, bO0.y, bO0.z, bO0.w, bO1.x, bO1.y, bO1.z, bO1.w};
#pragma unroll
    for (int e = 0; e < 8; ++e) {
      float hs = fmaxf(as[e] * xs[e] + bs[e], 0.f);
      float ho = fmaxf(ao[e] * xs[e] + bo[e], 0.f);
      unsigned short h1 = f2bf(hs);
      hsH[ks][e] = (short)h1;
      hsL[ks][e] = (short)f2bf(hs - bf2f(h1));
      unsigned short h2 = f2bf(ho);
      hoH[ks][e] = (short)h2;
      hoL[ks][e] = (short)f2bf(ho - bf2f(h2));
    }
  }
  __syncthreads();  // drain W staging
  f32x4 accS[8], accO[8];
#pragma unroll
  for (int j = 0; j < 8; ++j) {
    accS[j] = (f32x4){0.f, 0.f, 0.f, 0.f};
    accO[j] = (f32x4){0.f, 0.f, 0.f, 0.f};
  }
#pragma unroll
  for (int ks = 0; ks < 4; ++ks) {
    int kb = ks * 32 + lkc * 8;
#pragma unroll
    for (int jg = 0; jg < 8; ++jg) {
      int j = jg * 16 + lrow;
      int idx = j * 128 + (kb ^ ((j & 7) << 3));
      bf16x8 bsh = *(const bf16x8*)(&Wl[0][idx]);
      bf16x8 bsl = *(const bf16x8*)(&Wl[1][idx]);
      bf16x8 boh = *(const bf16x8*)(&Wl[2][idx]);
      bf16x8 bol = *(const bf16x8*)(&Wl[3][idx]);
      accS[jg] = __builtin_amdgcn_mfma_f32_16x16x32_bf16(hsH[ks], bsh, accS[jg], 0, 0, 0);
      accS[jg] = __builtin_amdgcn_mfma_f32_16x16x32_bf16(hsH[ks], bsl, accS[jg], 0, 0, 0);
      accS[jg] = __builtin_amdgcn_mfma_f32_16x16x32_bf16(hsL[ks], bsh, accS[jg], 0, 0, 0);
      accO[jg] = __builtin_amdgcn_mfma_f32_16x16x32_bf16(hoH[ks], boh, accO[jg], 0, 0, 0);
      accO[jg] = __builtin_amdgcn_mfma_f32_16x16x32_bf16(hoH[ks], bol, accO[jg], 0, 0, 0);
      accO[jg] = __builtin_amdgcn_mfma_f32_16x16x32_bf16(hoL[ks], boh, accO[jg], 0, 0, 0);
    }
  }
  __syncthreads();  // W consumed
#pragma unroll
  for (int jg = 0; jg < 8; ++jg) {
    int d = jg * 16 + lrow;
#pragma unroll
    for (int q = 0; q < 4; ++q) {
      int o = wr + lkc * 4 + q;
      int addr = d * 128 + (o ^ ((d & 7) << 3));
      float vv = accO[jg][q];
      unsigned short h = f2bf(vv);
      Wl[0][addr] = h;
      Wl[1][addr] = f2bf(vv - bf2f(h));
    }
  }
  __syncthreads();
  f32x4 accP[8];
#pragma unroll
  for (int j = 0; j < 8; ++j) accP[j] = (f32x4){0.f, 0.f, 0.f, 0.f};
#pragma unroll
  for (int ks = 0; ks < 4; ++ks) {
    int kb = ks * 32 + lkc * 8;
    bf16x8 pah, pal;
#pragma unroll
    for (int e = 0; e < 8; ++e) {
      float c = (float)au[ks][e];
      unsigned short hb = f2bf(c);
      pah[e] = (short)hb;
      pal[e] = (short)f2bf(c - bf2f(hb));
    }
#pragma unroll
    for (int jg = 0; jg < 8; ++jg) {
      int d = jg * 16 + lrow;
      int qi = d * 128 + (kb ^ ((d & 7) << 3));
      bf16x8 qh = *(const bf16x8*)(&Wl[0][qi]), ql = *(const bf16x8*)(&Wl[1][qi]);
      accP[jg] = __builtin_amdgcn_mfma_f32_16x16x32_bf16(pah, qh, accP[jg], 0, 0, 0);
      accP[jg] = __builtin_amdgcn_mfma_f32_16x16x32_bf16(pah, ql, accP[jg], 0, 0, 0);
      accP[jg] = __builtin_amdgcn_mfma_f32_16x16x32_bf16(pal, qh, accP[jg], 0, 0, 0);
    }
  }
  float lb[8];
#pragma unroll
  for (int jg = 0; jg < 8; ++jg) lb[jg] = lb1[jg * 16 + lrow];
  float sm[8], sq[8];
#pragma unroll
  for (int jg = 0; jg < 8; ++jg) { sm[jg] = 0.f; sq[jg] = 0.f; }
#pragma unroll
  for (int q = 0; q < 4; ++q) {
    int row = wr + lkc * 4 + q;
    size_t n = (size_t)v * kO + row;
    int cnt = cnt_s[n];
    float inv = (cnt > 0) ? 1.f / (float)cnt : 0.f;
#pragma unroll
    for (int jg = 0; jg < 8; ++jg) {
      int col = jg * 16 + lrow;
      float pv = 0.f;
      if (cnt > 0) pv = accS[jg][q] + lb[jg] + accP[jg][q] * inv;
      pooled[n * kD + col] = pv;
      sm[jg] += pv; sq[jg] += pv * pv;
    }
  }
  float* red = (float*)Wl[2];  // [32][128] f32 = 16 KiB
  int slot = wid * 4 + lkc;    // 0..31
#pragma unroll
  for (int jg = 0; jg < 8; ++jg) red[slot * 128 + jg * 16 + lrow] = sm[jg];
  __syncthreads();
  if (t < 128) {
    float s = 0.f;
#pragma unroll
    for (int g = 0; g < 32; ++g) s += red[g * 128 + t];
    p2[((size_t)v * 2 + 0) * 128 + t] = s;
  }
  __syncthreads();
#pragma unroll
  for (int jg = 0; jg < 8; ++jg) red[slot * 128 + jg * 16 + lrow] = sq[jg];
  __syncthreads();
  if (t < 128) {
    float s = 0.f;
#pragma unroll
    for (int g = 0; g < 32; ++g) s += red[g * 128 + t];
    p2[((size_t)v * 2 + 1) * 128 + t] = s;
  }
}

// ---- K6: finalize BN2 coeffs — 128 blocks (one per column), 256 partials ----
__global__ __launch_bounds__(256) void k_fin2(
    const float* __restrict__ p2, const float* __restrict__ g2,
    const float* __restrict__ b2, float* __restrict__ coef2) {
  __shared__ double sS[256], sQ[256];
  int d = blockIdx.x, t = threadIdx.x;
  double S = (double)p2[((size_t)t * 2 + 0) * 128 + d];
  double Q = (double)p2[((size_t)t * 2 + 1) * 128 + d];
  sS[t] = S; sQ[t] = Q;
  __syncthreads();
  for (int s = 128; s > 0; s >>= 1) {
    if (t < s) { sS[t] += sS[t + s]; sQ[t] += sQ[t + s]; }
    __syncthreads();
  }
  if (t == 0) {
    double m = sS[0] / (double)kN, var = sQ[0] / (double)kN - m * m;
    float a = g2[d] / sqrtf((float)var + kEps);
    float beta = b2[d] - (float)m * a;
    coef2[d] = a; coef2[128 + d] = beta;
  }
}

// ---- K7: W2 GEMM restructured like fused1: one block per graph (256 blocks),
// 512 threads; W2 image async-staged to LDS; per-lane A transform in regs;
// MFMA loop LDS/register-only. Optional fused next-BN1 stats.
template <int STATS>
__global__ __launch_bounds__(512, 2) void k_gemm(
    const float* __restrict__ X, const unsigned short* __restrict__ w2img,
    const float* __restrict__ coefA, const float* __restrict__ coefB,
    float* __restrict__ Y, const float* __restrict__ bias, const float* __restrict__ resid,
    const int* __restrict__ cnt_s, const int* __restrict__ cnt_o,
    float* __restrict__ p1out) {
  __shared__ __align__(16) unsigned short Wl[2][16384];  // hi,lo -> red
  int t = threadIdx.x, rb = blockIdx.x;  // rb = graph
  int lane = t & 63, wid = t >> 6;       // 8 waves, 16 rows each
  int wr = wid * 16, lrow = lane & 15, lkc = lane >> 4;
  int arow = wr + lrow;
  // stage W2 image (2 x 32 KB)
#pragma unroll
  for (int a = 0; a < 2; ++a)
#pragma unroll
    for (int i = 0; i < 4; ++i)
      __builtin_amdgcn_global_load_lds(
          (const unsigned int*)((const char*)(w2img + a * 16384) +
                                wid * 4096 + i * 1024 + lane * 16),
          (unsigned int*)((char*)Wl[a] + wid * 4096 + i * 1024), 16, 0, 0);
  // per-lane transform: X row -> bf16 hi/lo fragments in regs
  bf16x8 ahH[4], ahL[4];
#pragma unroll
  for (int ks = 0; ks < 4; ++ks) {
    int kb = ks * 32 + lkc * 8;
    float4 x0 = *(const float4*)(X + ((size_t)rb * kO + arow) * kD + kb);
    float4 x1 = *(const float4*)(X + ((size_t)rb * kO + arow) * kD + kb + 4);
    float4 a0 = *(const float4*)(coefA + kb), a1 = *(const float4*)(coefA + kb + 4);
    float4 b0 = *(const float4*)(coefB + kb), b1 = *(const float4*)(coefB + kb + 4);
    float xs[8] = {x0.x, x0.y, x0.z, x0.w, x1.x, x1.y, x1.z, x1.w};
    float as[8] = {a0.x, a0.y, a0.z, a0.w, a1.x, a1.y, a1.z, a1.w};
    float bs[8] = {b0.x, b0.y, b0.z, b0.w, b1.x, b1.y, b1.z, b1.w};
#pragma unroll
    for (int e = 0; e < 8; ++e) {
      float h = fmaxf(as[e] * xs[e] + bs[e], 0.f);
      unsigned short hb = f2bf(h);
      ahH[ks][e] = (short)hb;
      ahL[ks][e] = (short)f2bf(h - bf2f(hb));
    }
  }
  __syncthreads();  // drain W staging
  f32x4 acc[8];
#pragma unroll
  for (int j = 0; j < 8; ++j) acc[j] = (f32x4){0.f, 0.f, 0.f, 0.f};
#pragma unroll
  for (int ks = 0; ks < 4; ++ks) {
    int kb = ks * 32 + lkc * 8;
#pragma unroll
    for (int jg = 0; jg < 8; ++jg) {
      int j = jg * 16 + lrow;
      int idx = j * 128 + (kb ^ ((j & 7) << 3));
      bf16x8 bh = *(const bf16x8*)(&Wl[0][idx]);
      bf16x8 bl = *(const bf16x8*)(&Wl[1][idx]);
      acc[jg] = __builtin_amdgcn_mfma_f32_16x16x32_bf16(ahH[ks], bh, acc[jg], 0, 0, 0);
      acc[jg] = __builtin_amdgcn_mfma_f32_16x16x32_bf16(ahH[ks], bl, acc[jg], 0, 0, 0);
      acc[jg] = __builtin_amdgcn_mfma_f32_16x16x32_bf16(ahL[ks], bh, acc[jg], 0, 0, 0);
    }
  }
  // epilogue: bias (+resid) store; optional stats
  float s0[8], s1[8], s2[8], s3[8];
  if (STATS) {
#pragma unroll
    for (int jg = 0; jg < 8; ++jg) { s0[jg] = 0.f; s1[jg] = 0.f; s2[jg] = 0.f; s3[jg] = 0.f; }
  }
  float wsr[4], wor[4];
  if (STATS) {
#pragma unroll
    for (int q = 0; q < 4; ++q) {
      int n = rb * kO + wr + lkc * 4 + q;
      wsr[q] = (float)cnt_s[n]; wor[q] = (float)cnt_o[n];
    }
  }
#pragma unroll
  for (int jg = 0; jg < 8; ++jg) {
    int col = jg * 16 + lrow;
    float bcol = bias ? bias[col] : 0.f;
#pragma unroll
    for (int q = 0; q < 4; ++q) {
      int row = wr + lkc * 4 + q;
      size_t n = (size_t)rb * kO + row;
      float vv = acc[jg][q] + bcol;
      if (resid) vv += resid[n * kD + col];
      Y[n * kD + col] = vv;
      if (STATS) {
        s0[jg] += wsr[q] * vv; s1[jg] += wsr[q] * vv * vv;
        s2[jg] += wor[q] * vv; s3[jg] += wor[q] * vv * vv;
      }
    }
  }
  if (STATS) {
    __syncthreads();  // W consumed; reuse Wl as red [4][32][128] f32 = 64 KiB
    float* red = (float*)Wl;
    int slot = wid * 4 + lkc;  // 0..31
#pragma unroll
    for (int jg = 0; jg < 8; ++jg) {
      int col = jg * 16 + lrow;
      red[0 * 4096 + slot * 128 + col] = s0[jg];
      red[1 * 4096 + slot * 128 + col] = s1[jg];
      red[2 * 4096 + slot * 128 + col] = s2[jg];
      red[3 * 4096 + slot * 128 + col] = s3[jg];
    }
    __syncthreads();
    if (t < 128) {
#pragma unroll
      for (int st = 0; st < 4; ++st) {
        float s = 0.f;
#pragma unroll
        for (int g = 0; g < 32; ++g) s += red[st * 4096 + g * 128 + t];
        p1out[((size_t)rb * 4 + st) * 128 + t] = s;
      }
    }
  }
}

extern "C" void kernel_launch(void* const* d_in, const int* in_sizes, int n_in,
                              void* d_out, int out_size, void* d_ws, size_t ws_size,
                              hipStream_t stream) {
  (void)in_sizes; (void)n_in; (void)out_size; (void)ws_size;
  const float* obj = (const float*)d_in[0];
  const unsigned int* ew = (const unsigned int*)d_in[1];
  const float* prm[2][8];
  for (int u = 0; u < 2; ++u)
    for (int p = 0; p < 8; ++p) prm[u][p] = (const float*)d_in[2 + u * 8 + p];
  // prm[u]: 0=g1 1=b1 2=W1 3=lb1 4=g2 5=b2 6=W2 7=lb2

  char* ws = (char*)d_ws;
  size_t off = 0;
  auto carve = [&](size_t bytes) -> char* {
    char* p = ws + off;
    off = (off + bytes + 255) & ~(size_t)255;
    return p;
  };
  int* cnt_s = (int*)carve((size_t)kN * 4);
  int* cnt_o = (int*)carve((size_t)kN * 4);
  unsigned short* Au16 = (unsigned short*)carve((size_t)kV * 16384 * 2);
  float* p1 = (float*)carve((size_t)256 * 4 * 128 * 4);
  float* p2 = (float*)carve((size_t)kV * 2 * 128 * 4);
  float* coef1 = (float*)carve(512 * 4);
  float* coef2 = (float*)carve(256 * 4);
  unsigned short *w1img[2], *w2img[2];
  for (int u = 0; u < 2; ++u) {
    w1img[u] = (unsigned short*)carve((size_t)4 * 16384 * 2);  // 128 KB
    w2img[u] = (unsigned short*)carve((size_t)2 * 16384 * 2);  // 64 KB
  }
  float* pooled = (float*)carve((size_t)kN * kD * 4);
  float* x2 = (float*)carve((size_t)kN * kD * 4);

  k_adj<<<kV, 256, 0, stream>>>(ew, obj, cnt_s, cnt_o, Au16, p1);
  k_wsplit<<<128, 256, 0, stream>>>(prm[0][2], prm[0][6], prm[1][2], prm[1][6],
                                    w1img[0], w2img[0], w1img[1], w2img[1]);

  float* outp = (float*)d_out;
  // ---- unit 0 ----
  k_fin1<<<256, 256, 0, stream>>>(p1, prm[0][0], prm[0][1], coef1, 256);
  k_fused1<<<kV, 512, 0, stream>>>(obj, w1img[0], coef1, Au16,
                                   cnt_s, prm[0][3], pooled, p2);
  k_fin2<<<128, 256, 0, stream>>>(p2, prm[0][4], prm[0][5], coef2);
  k_gemm<1><<<kV, 512, 0, stream>>>(pooled, w2img[0], coef2, coef2 + 128,
                                    x2, prm[0][7], nullptr, cnt_s, cnt_o, p1);
  // ---- unit 1 ----
  k_fin1<<<256, 256, 0, stream>>>(p1, prm[1][0], prm[1][1], coef1, 256);
  k_fused1<<<kV, 512, 0, stream>>>(x2, w1img[1], coef1, Au16,
                                   cnt_s, prm[1][3], pooled, p2);
  k_fin2<<<128, 256, 0, stream>>>(p2, prm[1][4], prm[1][5], coef2);
  k_gemm<0><<<kV, 512, 0, stream>>>(pooled, w2img[1], coef2, coef2 + 128,
                                    outp, prm[1][7], obj, nullptr, nullptr, nullptr);
}

// Round 18
// 102.504 us; speedup vs baseline: 1.8203x; 1.0236x over previous
//
#include <hip/hip_runtime.h>

namespace {
constexpr int kV = 256, kO = 128, kE = 1024, kD = 128;
constexpr int kN = kV * kO;    // 32768 nodes
constexpr int kVE = kV * kE;   // 262144 edges
constexpr float kEps = 1e-5f;
}

typedef __attribute__((ext_vector_type(8))) short bf16x8;
typedef __attribute__((ext_vector_type(8))) unsigned short u16x8;
typedef __attribute__((ext_vector_type(4))) float f32x4;

__device__ __forceinline__ unsigned short f2bf(float x) {
  unsigned u = __float_as_uint(x);
  return (unsigned short)((u + 0x7FFFu + ((u >> 16) & 1u)) >> 16);
}
__device__ __forceinline__ float bf2f(unsigned short h) {
  return __uint_as_float((unsigned)h << 16);
}

// ---- K1 (merged): blocks 0..255 = per-graph adjacency (swizzled u16 A,
// degrees, fused unit-0 BN1 stats); blocks 256..287 = weight split
// (W1 -> 4x32KB swizzled LDS image; W2 -> 2x32KB swizzled LDS image).
__global__ __launch_bounds__(256) void k_init(
    const unsigned int* __restrict__ ew, const float* __restrict__ X,
    int* __restrict__ cnt_s, int* __restrict__ cnt_o,
    unsigned short* __restrict__ Au16, float* __restrict__ p1,
    const float* __restrict__ w1u0, const float* __restrict__ w2u0,
    const float* __restrict__ w1u1, const float* __restrict__ w2u1,
    unsigned short* __restrict__ img0, unsigned short* __restrict__ w2img0,
    unsigned short* __restrict__ img1, unsigned short* __restrict__ w2img1) {
  __shared__ int cnt[kO * kO];  // 64 KiB (reused as float red later)
  __shared__ int degS[kO], degO[kO];
  __shared__ int anyodd;
  int t = threadIdx.x;
  if (blockIdx.x >= 256) {
    // ---- weight-split path (32 blocks) ----
    const float* w1s[2] = {w1u0, w1u1};
    const float* w2s[2] = {w2u0, w2u1};
    unsigned short* img[2] = {img0, img1};
    unsigned short* w2i[2] = {w2img0, w2img1};
    int i0 = (blockIdx.x - 256) * 256 + t, stride = 32 * 256;
#pragma unroll
    for (int u = 0; u < 2; ++u) {
      for (int i = i0; i < kD * 2 * kD; i += stride) {
        int j = i >> 8, k = i & 255;
        int m = k >> 7, kk = k & 127;
        int pos = j * 128 + (kk ^ ((j & 7) << 3));
        float x = w1s[u][i];
        unsigned short hb = f2bf(x);
        img[u][(m * 2 + 0) * 16384 + pos] = hb;
        img[u][(m * 2 + 1) * 16384 + pos] = f2bf(x - bf2f(hb));
      }
      for (int i = i0; i < kD * kD; i += stride) {
        int j = i >> 7, kk = i & 127;
        int pos = j * 128 + (kk ^ ((j & 7) << 3));
        float x = w2s[u][i];
        unsigned short hb = f2bf(x);
        w2i[u][pos] = hb;
        w2i[u][16384 + pos] = f2bf(x - bf2f(hb));
      }
    }
    return;
  }
  // ---- adjacency path (256 blocks) ----
  int v = blockIdx.x;
  if (t == 0) anyodd = 0;
  for (int i = t; i < kO * kO; i += 256) cnt[i] = 0;
  __syncthreads();
  int base = v * 3072, loc = 0;
  for (int i = t; i < 3072; i += 256) {
    int g = base + i;
    if ((g & 1) && ew[g] != 0u) loc = 1;
  }
  if (loc) atomicOr(&anyodd, 1);
  __syncthreads();
  bool is64 = (anyodd == 0);
  for (int e = t; e < kE; e += 256) {
    long long eb = (long long)(v * kE + e) * 3;
    unsigned s, o;
    if (is64) { s = ew[2 * eb]; o = ew[2 * (eb + 2)]; }
    else      { s = ew[eb];     o = ew[eb + 2]; }
    s &= 127u; o &= 127u;
    atomicAdd(&cnt[s * kO + o], 1);
  }
  __syncthreads();
  unsigned int* A32 = (unsigned int*)(Au16 + (size_t)v * 16384);
  for (int i2 = t; i2 < 8192; i2 += 256) {
    int i = 2 * i2;
    int row = i >> 7, k = i & 127, kg = k >> 3;
    int j = row * 128 + ((kg ^ (row & 7)) << 3) + (k & 7);
    unsigned lo = (unsigned)cnt[i], hi = (unsigned)cnt[i + 1];
    A32[j >> 1] = lo | (hi << 16);
  }
  if (t < kO) {
    int s = 0;
    for (int c = 0; c < kO; ++c) s += cnt[t * kO + ((c + t) & 127)];
    degS[t] = s;
    cnt_s[v * kO + t] = s;
  } else {
    int tc = t - kO;
    int s = 0;
    for (int r = 0; r < kO; ++r) s += cnt[((r + tc) & 127) * kO + tc];
    degO[tc] = s;
    cnt_o[v * kO + tc] = s;
  }
  __syncthreads();
  int dq = (t & 31) * 4, rg = t >> 5;
  float acc[4][4];
#pragma unroll
  for (int a = 0; a < 4; ++a)
#pragma unroll
    for (int j = 0; j < 4; ++j) acc[a][j] = 0.f;
  for (int k = 0; k < 16; ++k) {
    int row = rg + k * 8;
    float4 xv = *(const float4*)(X + ((size_t)v * kO + row) * kD + dq);
    float wsv = (float)degS[row], wov = (float)degO[row];
    float xs[4] = {xv.x, xv.y, xv.z, xv.w};
#pragma unroll
    for (int j = 0; j < 4; ++j) {
      acc[0][j] += wsv * xs[j];
      acc[1][j] += wsv * xs[j] * xs[j];
      acc[2][j] += wov * xs[j];
      acc[3][j] += wov * xs[j] * xs[j];
    }
  }
  float* red = (float*)cnt;
  for (int st = 0; st < 4; ++st) {
    __syncthreads();
#pragma unroll
    for (int j = 0; j < 4; ++j) red[rg * 128 + dq + j] = acc[st][j];
    __syncthreads();
    if (t < 128) {
      float s = 0.f;
#pragma unroll
      for (int g = 0; g < 8; ++g) s += red[g * 128 + t];
      p1[((size_t)v * 4 + st) * 128 + t] = s;
    }
  }
}

// ---- K3: finalize BN1 coeffs — 256 blocks (one per column), nslots partials
__global__ __launch_bounds__(256) void k_fin1(
    const float* __restrict__ p1, const float* __restrict__ g1,
    const float* __restrict__ b1, float* __restrict__ coef, int nslots) {
  __shared__ double sS[256], sQ[256];
  int c = blockIdx.x, t = threadIdx.x;
  int half = c >> 7, d = c & 127;
  double S = 0.0, Q = 0.0;
  for (int b = t; b < nslots; b += 256) {
    S += (double)p1[((size_t)b * 4 + half * 2 + 0) * 128 + d];
    Q += (double)p1[((size_t)b * 4 + half * 2 + 1) * 128 + d];
  }
  sS[t] = S; sQ[t] = Q;
  __syncthreads();
  for (int s = 128; s > 0; s >>= 1) {
    if (t < s) { sS[t] += sS[t + s]; sQ[t] += sQ[t + s]; }
    __syncthreads();
  }
  if (t == 0) {
    double m = sS[0] / (double)kVE;
    double var = sQ[0] / (double)kVE - m * m;
    float a = g1[c] / sqrtf((float)var + kEps);
    float beta = b1[c] - (float)m * a;
    coef[half * 256 + d] = a;
    coef[half * 256 + 128 + d] = beta;
  }
}

// ---- K4: FUSED per-graph kernel (R16/R17, unchanged) ----
__global__ __launch_bounds__(512, 2) void k_fused1(
    const float* __restrict__ X, const unsigned short* __restrict__ w1img,
    const float* __restrict__ coef, const unsigned short* __restrict__ Au16,
    const int* __restrict__ cnt_s, const float* __restrict__ lb1,
    float* __restrict__ pooled, float* __restrict__ p2) {
  __shared__ __align__(16) unsigned short Wl[4][16384];  // sH,sL,oH,oL -> yoT/red
  int t = threadIdx.x, v = blockIdx.x;
  int lane = t & 63, wid = t >> 6;  // 8 waves, 16 rows each
  int wr = wid * 16, lrow = lane & 15, lkc = lane >> 4;
  int arow = wr + lrow;
#pragma unroll
  for (int a = 0; a < 4; ++a)
#pragma unroll
    for (int i = 0; i < 4; ++i)
      __builtin_amdgcn_global_load_lds(
          (const unsigned int*)((const char*)(w1img + a * 16384) +
                                wid * 4096 + i * 1024 + lane * 16),
          (unsigned int*)((char*)Wl[a] + wid * 4096 + i * 1024), 16, 0, 0);
  u16x8 au[4];
#pragma unroll
  for (int ks = 0; ks < 4; ++ks) {
    int kg = ks * 4 + lkc;
    au[ks] = *(const u16x8*)(Au16 + (size_t)v * 16384 + arow * 128 +
                             ((kg ^ (arow & 7)) << 3));
  }
  bf16x8 hsH[4], hsL[4], hoH[4], hoL[4];
#pragma unroll
  for (int ks = 0; ks < 4; ++ks) {
    int kb = ks * 32 + lkc * 8;
    float4 x0 = *(const float4*)(X + ((size_t)v * kO + arow) * kD + kb);
    float4 x1 = *(const float4*)(X + ((size_t)v * kO + arow) * kD + kb + 4);
    float4 aS0 = *(const float4*)(coef + kb),       aS1 = *(const float4*)(coef + kb + 4);
    float4 bS0 = *(const float4*)(coef + 128 + kb), bS1 = *(const float4*)(coef + 128 + kb + 4);
    float4 aO0 = *(const float4*)(coef + 256 + kb), aO1 = *(const float4*)(coef + 256 + kb + 4);
    float4 bO0 = *(const float4*)(coef + 384 + kb), bO1 = *(const float4*)(coef + 384 + kb + 4);
    float xs[8] = {x0.x, x0.y, x0.z, x0.w, x1.x, x1.y, x1.z, x1.w};
    float as[8] = {aS0.x, aS0.y, aS0.z, aS0.w, aS1.x, aS1.y, aS1.z, aS1.w};
    float bs[8] = {bS0.x, bS0.y, bS0.z, bS0.w, bS1.x, bS1.y, bS1.z, bS1.w};
    float ao[8] = {aO0.x, aO0.y, aO0.z, aO0.w, aO1.x, aO1.y, aO1.z, aO1.w};
    float bo[8] = {bO0.x, bO0.y, bO0.z, bO0.w, bO1.x, bO1.y, bO1.z, bO1.w};
#pragma unroll
    for (int e = 0; e < 8; ++e) {
      float hs = fmaxf(as[e] * xs[e] + bs[e], 0.f);
      float ho = fmaxf(ao[e] * xs[e] + bo[e], 0.f);
      unsigned short h1 = f2bf(hs);
      hsH[ks][e] = (short)h1;
      hsL[ks][e] = (short)f2bf(hs - bf2f(h1));
      unsigned short h2 = f2bf(ho);
      hoH[ks][e] = (short)h2;
      hoL[ks][e] = (short)f2bf(ho - bf2f(h2));
    }
  }
  __syncthreads();  // drain W staging
  f32x4 accS[8], accO[8];
#pragma unroll
  for (int j = 0; j < 8; ++j) {
    accS[j] = (f32x4){0.f, 0.f, 0.f, 0.f};
    accO[j] = (f32x4){0.f, 0.f, 0.f, 0.f};
  }
#pragma unroll
  for (int ks = 0; ks < 4; ++ks) {
    int kb = ks * 32 + lkc * 8;
#pragma unroll
    for (int jg = 0; jg < 8; ++jg) {
      int j = jg * 16 + lrow;
      int idx = j * 128 + (kb ^ ((j & 7) << 3));
      bf16x8 bsh = *(const bf16x8*)(&Wl[0][idx]);
      bf16x8 bsl = *(const bf16x8*)(&Wl[1][idx]);
      bf16x8 boh = *(const bf16x8*)(&Wl[2][idx]);
      bf16x8 bol = *(const bf16x8*)(&Wl[3][idx]);
      accS[jg] = __builtin_amdgcn_mfma_f32_16x16x32_bf16(hsH[ks], bsh, accS[jg], 0, 0, 0);
      accS[jg] = __builtin_amdgcn_mfma_f32_16x16x32_bf16(hsH[ks], bsl, accS[jg], 0, 0, 0);
      accS[jg] = __builtin_amdgcn_mfma_f32_16x16x32_bf16(hsL[ks], bsh, accS[jg], 0, 0, 0);
      accO[jg] = __builtin_amdgcn_mfma_f32_16x16x32_bf16(hoH[ks], boh, accO[jg], 0, 0, 0);
      accO[jg] = __builtin_amdgcn_mfma_f32_16x16x32_bf16(hoH[ks], bol, accO[jg], 0, 0, 0);
      accO[jg] = __builtin_amdgcn_mfma_f32_16x16x32_bf16(hoL[ks], boh, accO[jg], 0, 0, 0);
    }
  }
  __syncthreads();  // W consumed
#pragma unroll
  for (int jg = 0; jg < 8; ++jg) {
    int d = jg * 16 + lrow;
#pragma unroll
    for (int q = 0; q < 4; ++q) {
      int o = wr + lkc * 4 + q;
      int addr = d * 128 + (o ^ ((d & 7) << 3));
      float vv = accO[jg][q];
      unsigned short h = f2bf(vv);
      Wl[0][addr] = h;
      Wl[1][addr] = f2bf(vv - bf2f(h));
    }
  }
  __syncthreads();
  f32x4 accP[8];
#pragma unroll
  for (int j = 0; j < 8; ++j) accP[j] = (f32x4){0.f, 0.f, 0.f, 0.f};
#pragma unroll
  for (int ks = 0; ks < 4; ++ks) {
    int kb = ks * 32 + lkc * 8;
    bf16x8 pah, pal;
#pragma unroll
    for (int e = 0; e < 8; ++e) {
      float c = (float)au[ks][e];
      unsigned short hb = f2bf(c);
      pah[e] = (short)hb;
      pal[e] = (short)f2bf(c - bf2f(hb));
    }
#pragma unroll
    for (int jg = 0; jg < 8; ++jg) {
      int d = jg * 16 + lrow;
      int qi = d * 128 + (kb ^ ((d & 7) << 3));
      bf16x8 qh = *(const bf16x8*)(&Wl[0][qi]), ql = *(const bf16x8*)(&Wl[1][qi]);
      accP[jg] = __builtin_amdgcn_mfma_f32_16x16x32_bf16(pah, qh, accP[jg], 0, 0, 0);
      accP[jg] = __builtin_amdgcn_mfma_f32_16x16x32_bf16(pah, ql, accP[jg], 0, 0, 0);
      accP[jg] = __builtin_amdgcn_mfma_f32_16x16x32_bf16(pal, qh, accP[jg], 0, 0, 0);
    }
  }
  float lb[8];
#pragma unroll
  for (int jg = 0; jg < 8; ++jg) lb[jg] = lb1[jg * 16 + lrow];
  float sm[8], sq[8];
#pragma unroll
  for (int jg = 0; jg < 8; ++jg) { sm[jg] = 0.f; sq[jg] = 0.f; }
#pragma unroll
  for (int q = 0; q < 4; ++q) {
    int row = wr + lkc * 4 + q;
    size_t n = (size_t)v * kO + row;
    int cnt = cnt_s[n];
    float inv = (cnt > 0) ? 1.f / (float)cnt : 0.f;
#pragma unroll
    for (int jg = 0; jg < 8; ++jg) {
      int col = jg * 16 + lrow;
      float pv = 0.f;
      if (cnt > 0) pv = accS[jg][q] + lb[jg] + accP[jg][q] * inv;
      pooled[n * kD + col] = pv;
      sm[jg] += pv; sq[jg] += pv * pv;
    }
  }
  float* red = (float*)Wl[2];  // [32][128] f32 = 16 KiB
  int slot = wid * 4 + lkc;    // 0..31
#pragma unroll
  for (int jg = 0; jg < 8; ++jg) red[slot * 128 + jg * 16 + lrow] = sm[jg];
  __syncthreads();
  if (t < 128) {
    float s = 0.f;
#pragma unroll
    for (int g = 0; g < 32; ++g) s += red[g * 128 + t];
    p2[((size_t)v * 2 + 0) * 128 + t] = s;
  }
  __syncthreads();
#pragma unroll
  for (int jg = 0; jg < 8; ++jg) red[slot * 128 + jg * 16 + lrow] = sq[jg];
  __syncthreads();
  if (t < 128) {
    float s = 0.f;
#pragma unroll
    for (int g = 0; g < 32; ++g) s += red[g * 128 + t];
    p2[((size_t)v * 2 + 1) * 128 + t] = s;
  }
}

// ---- K6: finalize BN2 coeffs — 128 blocks (one per column), 256 partials ----
__global__ __launch_bounds__(256) void k_fin2(
    const float* __restrict__ p2, const float* __restrict__ g2,
    const float* __restrict__ b2, float* __restrict__ coef2) {
  __shared__ double sS[256], sQ[256];
  int d = blockIdx.x, t = threadIdx.x;
  double S = (double)p2[((size_t)t * 2 + 0) * 128 + d];
  double Q = (double)p2[((size_t)t * 2 + 1) * 128 + d];
  sS[t] = S; sQ[t] = Q;
  __syncthreads();
  for (int s = 128; s > 0; s >>= 1) {
    if (t < s) { sS[t] += sS[t + s]; sQ[t] += sQ[t + s]; }
    __syncthreads();
  }
  if (t == 0) {
    double m = sS[0] / (double)kN, var = sQ[0] / (double)kN - m * m;
    float a = g2[d] / sqrtf((float)var + kEps);
    float beta = b2[d] - (float)m * a;
    coef2[d] = a; coef2[128 + d] = beta;
  }
}

// ---- K7: W2 GEMM (R17, unchanged): one block per graph, 512 threads,
// W2 image async-staged to LDS; per-lane A transform in regs. ----
template <int STATS>
__global__ __launch_bounds__(512, 2) void k_gemm(
    const float* __restrict__ X, const unsigned short* __restrict__ w2img,
    const float* __restrict__ coefA, const float* __restrict__ coefB,
    float* __restrict__ Y, const float* __restrict__ bias, const float* __restrict__ resid,
    const int* __restrict__ cnt_s, const int* __restrict__ cnt_o,
    float* __restrict__ p1out) {
  __shared__ __align__(16) unsigned short Wl[2][16384];  // hi,lo -> red
  int t = threadIdx.x, rb = blockIdx.x;  // rb = graph
  int lane = t & 63, wid = t >> 6;       // 8 waves, 16 rows each
  int wr = wid * 16, lrow = lane & 15, lkc = lane >> 4;
  int arow = wr + lrow;
#pragma unroll
  for (int a = 0; a < 2; ++a)
#pragma unroll
    for (int i = 0; i < 4; ++i)
      __builtin_amdgcn_global_load_lds(
          (const unsigned int*)((const char*)(w2img + a * 16384) +
                                wid * 4096 + i * 1024 + lane * 16),
          (unsigned int*)((char*)Wl[a] + wid * 4096 + i * 1024), 16, 0, 0);
  bf16x8 ahH[4], ahL[4];
#pragma unroll
  for (int ks = 0; ks < 4; ++ks) {
    int kb = ks * 32 + lkc * 8;
    float4 x0 = *(const float4*)(X + ((size_t)rb * kO + arow) * kD + kb);
    float4 x1 = *(const float4*)(X + ((size_t)rb * kO + arow) * kD + kb + 4);
    float4 a0 = *(const float4*)(coefA + kb), a1 = *(const float4*)(coefA + kb + 4);
    float4 b0 = *(const float4*)(coefB + kb), b1 = *(const float4*)(coefB + kb + 4);
    float xs[8] = {x0.x, x0.y, x0.z, x0.w, x1.x, x1.y, x1.z, x1.w};
    float as[8] = {a0.x, a0.y, a0.z, a0.w, a1.x, a1.y, a1.z, a1.w};
    float bs[8] = {b0.x, b0.y, b0.z, b0.w, b1.x, b1.y, b1.z, b1.w};
#pragma unroll
    for (int e = 0; e < 8; ++e) {
      float h = fmaxf(as[e] * xs[e] + bs[e], 0.f);
      unsigned short hb = f2bf(h);
      ahH[ks][e] = (short)hb;
      ahL[ks][e] = (short)f2bf(h - bf2f(hb));
    }
  }
  __syncthreads();  // drain W staging
  f32x4 acc[8];
#pragma unroll
  for (int j = 0; j < 8; ++j) acc[j] = (f32x4){0.f, 0.f, 0.f, 0.f};
#pragma unroll
  for (int ks = 0; ks < 4; ++ks) {
    int kb = ks * 32 + lkc * 8;
#pragma unroll
    for (int jg = 0; jg < 8; ++jg) {
      int j = jg * 16 + lrow;
      int idx = j * 128 + (kb ^ ((j & 7) << 3));
      bf16x8 bh = *(const bf16x8*)(&Wl[0][idx]);
      bf16x8 bl = *(const bf16x8*)(&Wl[1][idx]);
      acc[jg] = __builtin_amdgcn_mfma_f32_16x16x32_bf16(ahH[ks], bh, acc[jg], 0, 0, 0);
      acc[jg] = __builtin_amdgcn_mfma_f32_16x16x32_bf16(ahH[ks], bl, acc[jg], 0, 0, 0);
      acc[jg] = __builtin_amdgcn_mfma_f32_16x16x32_bf16(ahL[ks], bh, acc[jg], 0, 0, 0);
    }
  }
  float s0[8], s1[8], s2[8], s3[8];
  if (STATS) {
#pragma unroll
    for (int jg = 0; jg < 8; ++jg) { s0[jg] = 0.f; s1[jg] = 0.f; s2[jg] = 0.f; s3[jg] = 0.f; }
  }
  float wsr[4], wor[4];
  if (STATS) {
#pragma unroll
    for (int q = 0; q < 4; ++q) {
      int n = rb * kO + wr + lkc * 4 + q;
      wsr[q] = (float)cnt_s[n]; wor[q] = (float)cnt_o[n];
    }
  }
#pragma unroll
  for (int jg = 0; jg < 8; ++jg) {
    int col = jg * 16 + lrow;
    float bcol = bias ? bias[col] : 0.f;
#pragma unroll
    for (int q = 0; q < 4; ++q) {
      int row = wr + lkc * 4 + q;
      size_t n = (size_t)rb * kO + row;
      float vv = acc[jg][q] + bcol;
      if (resid) vv += resid[n * kD + col];
      Y[n * kD + col] = vv;
      if (STATS) {
        s0[jg] += wsr[q] * vv; s1[jg] += wsr[q] * vv * vv;
        s2[jg] += wor[q] * vv; s3[jg] += wor[q] * vv * vv;
      }
    }
  }
  if (STATS) {
    __syncthreads();  // W consumed; reuse Wl as red [4][32][128] f32 = 64 KiB
    float* red = (float*)Wl;
    int slot = wid * 4 + lkc;  // 0..31
#pragma unroll
    for (int jg = 0; jg < 8; ++jg) {
      int col = jg * 16 + lrow;
      red[0 * 4096 + slot * 128 + col] = s0[jg];
      red[1 * 4096 + slot * 128 + col] = s1[jg];
      red[2 * 4096 + slot * 128 + col] = s2[jg];
      red[3 * 4096 + slot * 128 + col] = s3[jg];
    }
    __syncthreads();
    if (t < 128) {
#pragma unroll
      for (int st = 0; st < 4; ++st) {
        float s = 0.f;
#pragma unroll
        for (int g = 0; g < 32; ++g) s += red[st * 4096 + g * 128 + t];
        p1out[((size_t)rb * 4 + st) * 128 + t] = s;
      }
    }
  }
}

extern "C" void kernel_launch(void* const* d_in, const int* in_sizes, int n_in,
                              void* d_out, int out_size, void* d_ws, size_t ws_size,
                              hipStream_t stream) {
  (void)in_sizes; (void)n_in; (void)out_size; (void)ws_size;
  const float* obj = (const float*)d_in[0];
  const unsigned int* ew = (const unsigned int*)d_in[1];
  const float* prm[2][8];
  for (int u = 0; u < 2; ++u)
    for (int p = 0; p < 8; ++p) prm[u][p] = (const float*)d_in[2 + u * 8 + p];
  // prm[u]: 0=g1 1=b1 2=W1 3=lb1 4=g2 5=b2 6=W2 7=lb2

  char* ws = (char*)d_ws;
  size_t off = 0;
  auto carve = [&](size_t bytes) -> char* {
    char* p = ws + off;
    off = (off + bytes + 255) & ~(size_t)255;
    return p;
  };
  int* cnt_s = (int*)carve((size_t)kN * 4);
  int* cnt_o = (int*)carve((size_t)kN * 4);
  unsigned short* Au16 = (unsigned short*)carve((size_t)kV * 16384 * 2);
  float* p1 = (float*)carve((size_t)256 * 4 * 128 * 4);
  float* p2 = (float*)carve((size_t)kV * 2 * 128 * 4);
  float* coef1 = (float*)carve(512 * 4);
  float* coef2 = (float*)carve(256 * 4);
  unsigned short *w1img[2], *w2img[2];
  for (int u = 0; u < 2; ++u) {
    w1img[u] = (unsigned short*)carve((size_t)4 * 16384 * 2);  // 128 KB
    w2img[u] = (unsigned short*)carve((size_t)2 * 16384 * 2);  // 64 KB
  }
  float* pooled = (float*)carve((size_t)kN * kD * 4);
  float* x2 = (float*)carve((size_t)kN * kD * 4);

  k_init<<<288, 256, 0, stream>>>(ew, obj, cnt_s, cnt_o, Au16, p1,
                                  prm[0][2], prm[0][6], prm[1][2], prm[1][6],
                                  w1img[0], w2img[0], w1img[1], w2img[1]);

  float* outp = (float*)d_out;
  // ---- unit 0 ----
  k_fin1<<<256, 256, 0, stream>>>(p1, prm[0][0], prm[0][1], coef1, 256);
  k_fused1<<<kV, 512, 0, stream>>>(obj, w1img[0], coef1, Au16,
                                   cnt_s, prm[0][3], pooled, p2);
  k_fin2<<<128, 256, 0, stream>>>(p2, prm[0][4], prm[0][5], coef2);
  k_gemm<1><<<kV, 512, 0, stream>>>(pooled, w2img[0], coef2, coef2 + 128,
                                    x2, prm[0][7], nullptr, cnt_s, cnt_o, p1);
  // ---- unit 1 ----
  k_fin1<<<256, 256, 0, stream>>>(p1, prm[1][0], prm[1][1], coef1, 256);
  k_fused1<<<kV, 512, 0, stream>>>(x2, w1img[1], coef1, Au16,
                                   cnt_s, prm[1][3], pooled, p2);
  k_fin2<<<128, 256, 0, stream>>>(p2, prm[1][4], prm[1][5], coef2);
  k_gemm<0><<<kV, 512, 0, stream>>>(pooled, w2img[1], coef2, coef2 + 128,
                                    outp, prm[1][7], obj, nullptr, nullptr, nullptr);
}